// Round 1
// baseline (24782.713 us; speedup 1.0000x reference)
//
#include <hip/hip_runtime.h>
#include <hip/hip_bf16.h>
#include <stdint.h>

typedef unsigned int  u32;
typedef unsigned short u16;

#define TSTEPS 1024
#define BATCH  512
#define INDIM  32
#define HID    256
#define ODIM   32

// ---------------- workspace layout (bytes) ----------------
// Wp : u16[128][256][8]  = 512 KB  @ 0        (W_hh packed: [m2][k][p][g])
// Xp : u16[16][256][8]   =  64 KB  @ 524288   (W_ih packed: [j2][k][p][g])
// Bp : float[256][4]     =   4 KB  @ 589824   (b_ih+b_hh packed per hidden unit)
// WoT: float[256][32]    =  32 KB  @ 593920   (W_out transposed [k][o])
// total 626,688 bytes

#define WS_XP  524288
#define WS_BP  589824
#define WS_WOT 593920

__device__ __forceinline__ u16 f2bf(float v) {
    __hip_bfloat16 b = __float2bfloat16(v);
    return *reinterpret_cast<u16*>(&b);
}

__global__ __launch_bounds__(256) void prepack_kernel(
    const float* __restrict__ W_ih, const float* __restrict__ W_hh,
    const float* __restrict__ b_ih, const float* __restrict__ b_hh,
    const float* __restrict__ W_out,
    u16* __restrict__ Wp, u16* __restrict__ Xp,
    float* __restrict__ Bp, float* __restrict__ WoT)
{
    int tid    = blockIdx.x * blockDim.x + threadIdx.x;
    int stride = gridDim.x * blockDim.x;

    // Wp[((m2*256 + k)*2 + p)*4 + g] = bf16( W_hh[(g*256+k)*256 + 2*m2+p] )
    for (int idx = tid; idx < 128 * 256 * 8; idx += stride) {
        int g  = idx & 3;
        int p  = (idx >> 2) & 1;
        int k  = (idx >> 3) & 255;
        int m2 = idx >> 11;
        Wp[idx] = f2bf(W_hh[(g * HID + k) * HID + (2 * m2 + p)]);
    }
    // Xp[((j2*256 + k)*2 + p)*4 + g] = bf16( W_ih[(g*256+k)*32 + 2*j2+p] )
    for (int idx = tid; idx < 16 * 256 * 8; idx += stride) {
        int g  = idx & 3;
        int p  = (idx >> 2) & 1;
        int k  = (idx >> 3) & 255;
        int j2 = idx >> 11;
        Xp[idx] = f2bf(W_ih[(g * HID + k) * INDIM + (2 * j2 + p)]);
    }
    // Bp[k*4+g] = b_ih[g*256+k] + b_hh[g*256+k]
    for (int idx = tid; idx < HID * 4; idx += stride) {
        int g = idx & 3;
        int k = idx >> 2;
        Bp[idx] = b_ih[g * HID + k] + b_hh[g * HID + k];
    }
    // WoT[k*32+o] = W_out[o*256+k]
    for (int idx = tid; idx < HID * ODIM; idx += stride) {
        int o = idx & 31;
        int k = idx >> 5;
        WoT[idx] = W_out[o * HID + k];
    }
}

__device__ __forceinline__ float sigf(float x) {
    return 1.0f / (1.0f + __expf(-x));
}
__device__ __forceinline__ float tanhf_(float x) {
    float ax = fabsf(x);
    float e  = __expf(-2.0f * ax);           // in (0,1], no overflow
    float t  = (1.0f - e) / (1.0f + e);
    return copysignf(t, x);
}

// one block = 2 batch rows; one thread = 1 hidden unit (all 4 gates)
__global__ __launch_bounds__(256) void lstm_kernel(
    const float* __restrict__ xin,    // [T][B][32]
    const float* __restrict__ phys,   // [T][B][32]
    const u16*   __restrict__ Wp,     // packed bf16 recurrent weights
    const u16*   __restrict__ Xp,     // packed bf16 input weights
    const float* __restrict__ Bp,     // [256][4] combined bias
    const float* __restrict__ WoT,    // [256][32]
    const float* __restrict__ b_out,  // [32]
    float* __restrict__ out)          // [2][B][T][32] concat
{
    const int k  = threadIdx.x;        // hidden unit
    const int b0 = blockIdx.x * 2;     // first batch row of this block

    __shared__ __align__(16) float h_lds[HID * 2];   // [m][r]
    __shared__ __align__(16) float x_lds[INDIM * 2]; // [j][r]

    float c0 = 0.0f, c1 = 0.0f;
    h_lds[2 * k]     = 0.0f;
    h_lds[2 * k + 1] = 0.0f;

    const uint4*  Wp4 = (const uint4*)Wp;   // index m2*256 + k
    const uint4*  Xp4 = (const uint4*)Xp;   // index j2*256 + k
    const float4  bias = ((const float4*)Bp)[k];
    const float4* h4 = (const float4*)h_lds;
    const float4* x4 = (const float4*)x_lds;

    float* outFull = out;
    float* outRnn  = out + (size_t)BATCH * TSTEPS * ODIM;

    // per-thread constants for output-projection phase
    const int   q_  = k & 3;
    const int   r_  = k >> 7;
    const int   o_  = (k >> 2) & 31;
    const float bo_ = b_out[o_];

#define DECODE_FMA(wa, wb, hr0, hr1)                         \
    {                                                        \
        float w_i = __uint_as_float((wa) << 16);             \
        float w_f = __uint_as_float((wa) & 0xffff0000u);     \
        float w_g = __uint_as_float((wb) << 16);             \
        float w_o = __uint_as_float((wb) & 0xffff0000u);     \
        a0i = __builtin_fmaf(w_i, (hr0), a0i);               \
        a1i = __builtin_fmaf(w_i, (hr1), a1i);               \
        a0f = __builtin_fmaf(w_f, (hr0), a0f);               \
        a1f = __builtin_fmaf(w_f, (hr1), a1f);               \
        a0g = __builtin_fmaf(w_g, (hr0), a0g);               \
        a1g = __builtin_fmaf(w_g, (hr1), a1g);               \
        a0o = __builtin_fmaf(w_o, (hr0), a0o);               \
        a1o = __builtin_fmaf(w_o, (hr1), a1o);               \
    }

    for (int t = 0; t < TSTEPS; ++t) {
        // stage x_t for this block's 2 rows
        if (k < 64) {
            int r = k >> 5, j = k & 31;
            x_lds[j * 2 + r] = xin[(size_t)t * BATCH * INDIM + (size_t)(b0 + r) * INDIM + j];
        }
        __syncthreads();   // sync1: x ready, h_lds stable

        float a0i = bias.x, a0f = bias.y, a0g = bias.z, a0o = bias.w;
        float a1i = bias.x, a1f = bias.y, a1g = bias.z, a1o = bias.w;

        // x @ W_ih^T contribution (16 packed pairs)
#pragma unroll 4
        for (int j2 = 0; j2 < INDIM / 2; ++j2) {
            uint4  w  = Xp4[(j2 << 8) + k];
            float4 xv = x4[j2];
            DECODE_FMA(w.x, w.y, xv.x, xv.y);
            DECODE_FMA(w.z, w.w, xv.z, xv.w);
        }

        // h @ W_hh^T contribution (128 packed pairs), weights streamed from L2
#pragma unroll 8
        for (int m2 = 0; m2 < HID / 2; ++m2) {
            uint4  w  = Wp4[(m2 << 8) + k];
            float4 hv = h4[m2];
            DECODE_FMA(w.x, w.y, hv.x, hv.y);
            DECODE_FMA(w.z, w.w, hv.z, hv.w);
        }

        // LSTM cell update (fp32)
        float i0 = sigf(a0i), f0 = sigf(a0f), g0 = tanhf_(a0g), o0 = sigf(a0o);
        float i1 = sigf(a1i), f1 = sigf(a1f), g1 = tanhf_(a1g), o1 = sigf(a1o);
        c0 = f0 * c0 + i0 * g0;
        c1 = f1 * c1 + i1 * g1;
        float h0 = o0 * tanhf_(c0);
        float h1 = o1 * tanhf_(c1);

        __syncthreads();   // sync2: all reads of old h done
        h_lds[2 * k]     = h0;
        h_lds[2 * k + 1] = h1;
        __syncthreads();   // sync3: new h visible

        // output projection: 64 (row,o) pairs x 4 threads each (64-elem partial dots)
        {
            float s = 0.0f;
#pragma unroll 16
            for (int j = 0; j < 64; ++j) {
                int kk = (q_ << 6) + j;
                s += h_lds[kk * 2 + r_] * WoT[(kk << 5) + o_];
            }
            s += __shfl_xor(s, 1);
            s += __shfl_xor(s, 2);
            if (q_ == 0) {
                float rp = s + bo_;
                size_t iob = (size_t)(b0 + r_) * TSTEPS * ODIM + (size_t)t * ODIM + o_;
                float  ph  = phys[(size_t)t * BATCH * ODIM + (size_t)(b0 + r_) * ODIM + o_];
                outFull[iob] = ph + rp;
                outRnn[iob]  = rp;
            }
        }
    }
#undef DECODE_FMA
}

extern "C" void kernel_launch(void* const* d_in, const int* in_sizes, int n_in,
                              void* d_out, int out_size, void* d_ws, size_t ws_size,
                              hipStream_t stream) {
    const float* xin   = (const float*)d_in[0];
    const float* phys  = (const float*)d_in[1];
    const float* W_ih  = (const float*)d_in[2];
    const float* W_hh  = (const float*)d_in[3];
    const float* b_ih  = (const float*)d_in[4];
    const float* b_hh  = (const float*)d_in[5];
    const float* W_out = (const float*)d_in[6];
    const float* b_out = (const float*)d_in[7];

    char* ws = (char*)d_ws;
    u16*   Wp  = (u16*)ws;
    u16*   Xp  = (u16*)(ws + WS_XP);
    float* Bp  = (float*)(ws + WS_BP);
    float* WoT = (float*)(ws + WS_WOT);

    prepack_kernel<<<256, 256, 0, stream>>>(W_ih, W_hh, b_ih, b_hh, W_out, Wp, Xp, Bp, WoT);
    lstm_kernel<<<256, 256, 0, stream>>>(xin, phys, Wp, Xp, Bp, WoT, b_out, (float*)d_out);
}

// Round 2
// 18232.388 us; speedup vs baseline: 1.3593x; 1.3593x over previous
//
#include <hip/hip_runtime.h>
#include <hip/hip_bf16.h>
#include <stdint.h>

typedef unsigned int  u32;
typedef unsigned short u16;

#define TSTEPS 1024
#define BATCH  512
#define INDIM  32
#define HID    256
#define ODIM   32

// ---------------- workspace layout (bytes) ----------------
// Wp : u16[128][256][8]  = 512 KB  @ 0        (W_hh packed: [kk2][m][p][g])
// Xp : u16[16][256][8]   =  64 KB  @ 524288   (W_ih packed: [j2][m][p][g])
// Bp : float[256][4]     =   4 KB  @ 589824   (b_ih+b_hh packed per hidden unit)

#define WS_XP  524288
#define WS_BP  589824

__device__ __forceinline__ u16 f2bf(float v) {
    __hip_bfloat16 b = __float2bfloat16(v);
    return *reinterpret_cast<u16*>(&b);
}

__global__ __launch_bounds__(256) void prepack_kernel(
    const float* __restrict__ W_ih, const float* __restrict__ W_hh,
    const float* __restrict__ b_ih, const float* __restrict__ b_hh,
    u16* __restrict__ Wp, u16* __restrict__ Xp, float* __restrict__ Bp)
{
    int tid    = blockIdx.x * blockDim.x + threadIdx.x;
    int stride = gridDim.x * blockDim.x;

    // Wp[((kk2*256 + m)*2 + p)*4 + g] = bf16( W_hh[(g*256+m)*256 + 2*kk2+p] )
    for (int idx = tid; idx < 128 * 256 * 8; idx += stride) {
        int g   = idx & 3;
        int p   = (idx >> 2) & 1;
        int m   = (idx >> 3) & 255;
        int kk2 = idx >> 11;
        Wp[idx] = f2bf(W_hh[(g * HID + m) * HID + (2 * kk2 + p)]);
    }
    // Xp[((j2*256 + m)*2 + p)*4 + g] = bf16( W_ih[(g*256+m)*32 + 2*j2+p] )
    for (int idx = tid; idx < 16 * 256 * 8; idx += stride) {
        int g  = idx & 3;
        int p  = (idx >> 2) & 1;
        int m  = (idx >> 3) & 255;
        int j2 = idx >> 11;
        Xp[idx] = f2bf(W_ih[(g * HID + m) * INDIM + (2 * j2 + p)]);
    }
    // Bp[m*4+g] = b_ih[g*256+m] + b_hh[g*256+m]
    for (int idx = tid; idx < HID * 4; idx += stride) {
        int g = idx & 3;
        int m = idx >> 2;
        Bp[idx] = b_ih[g * HID + m] + b_hh[g * HID + m];
    }
}

__device__ __forceinline__ float sigf(float x) {
    return 1.0f / (1.0f + __expf(-x));
}
__device__ __forceinline__ float tanhf_(float x) {
    float ax = fabsf(x);
    float e  = __expf(-2.0f * ax);           // in (0,1], no overflow
    float t  = (1.0f - e) / (1.0f + e);
    return copysignf(t, x);
}

// one block = 2 batch rows; 1024 threads = 256 hidden units x 4 k-quarters.
// thread (m, q4): q4 = tid&3 in adjacent lanes -> shuffle reduction.
__global__ __launch_bounds__(1024, 1) void lstm_kernel(
    const float* __restrict__ xin,    // [T][B][32]
    const float* __restrict__ phys,   // [T][B][32]
    const u16*   __restrict__ Wp,     // packed bf16 recurrent weights
    const u16*   __restrict__ Xp,     // packed bf16 input weights
    const float* __restrict__ Bp,     // [256][4] combined bias
    const float* __restrict__ W_out,  // [32][256] row-major
    const float* __restrict__ b_out,  // [32]
    float* __restrict__ out)          // [2][B][T][32] concat
{
    const int tid = threadIdx.x;
    const int q4  = tid & 3;          // k-quarter
    const int m   = tid >> 2;         // hidden unit
    const int b0  = blockIdx.x * 2;   // first batch row of this block

    __shared__ __align__(16) float h_lds[HID * 2];       // [unit][row]
    __shared__ __align__(16) float x_lds[INDIM * 2];     // [j][row]
    __shared__ __align__(16) float wot_lds[ODIM * 264];  // [o][k] padded stride 264

    float c0 = 0.0f, c1 = 0.0f;
    if (tid < HID * 2) h_lds[tid] = 0.0f;
    // stage W_out (already [o][k] row-major) into padded LDS, coalesced
    for (int idx = tid; idx < ODIM * HID; idx += 1024)
        wot_lds[(idx >> 8) * 264 + (idx & 255)] = W_out[idx];

    const uint4*  Wp4 = (const uint4*)Wp;   // [kk2][m]
    const uint4*  Xp4 = (const uint4*)Xp;   // [j2][m]
    const float4* h4  = (const float4*)h_lds;
    const float4* x4  = (const float4*)x_lds;

    const float4 bias  = ((const float4*)Bp)[m];
    const float4 zero4 = make_float4(0.f, 0.f, 0.f, 0.f);
    const float4 binit = (q4 == 0) ? bias : zero4;   // bias counted once per unit

    float* outFull = out;
    float* outRnn  = out + (size_t)BATCH * TSTEPS * ODIM;

    // projection-phase constants: 64 items (2 rows x 32 o), 16 lanes each
    const int   sub  = tid & 15;
    const int   item = tid >> 4;
    const int   o_   = item & 31;
    const int   r_   = item >> 5;
    const float bo_  = b_out[o_];

#define DECODE_FMA(wa, wb, hr0, hr1)                         \
    {                                                        \
        float w_i = __uint_as_float((wa) << 16);             \
        float w_f = __uint_as_float((wa) & 0xffff0000u);     \
        float w_g = __uint_as_float((wb) << 16);             \
        float w_o = __uint_as_float((wb) & 0xffff0000u);     \
        a0i = __builtin_fmaf(w_i, (hr0), a0i);               \
        a1i = __builtin_fmaf(w_i, (hr1), a1i);               \
        a0f = __builtin_fmaf(w_f, (hr0), a0f);               \
        a1f = __builtin_fmaf(w_f, (hr1), a1f);               \
        a0g = __builtin_fmaf(w_g, (hr0), a0g);               \
        a1g = __builtin_fmaf(w_g, (hr1), a1g);               \
        a0o = __builtin_fmaf(w_o, (hr0), a0o);               \
        a1o = __builtin_fmaf(w_o, (hr1), a1o);               \
    }

    for (int t = 0; t < TSTEPS; ++t) {
        // stage x_t for this block's 2 rows (64 consecutive floats)
        if (tid < 64) {
            int r = tid >> 5, j = tid & 31;
            x_lds[j * 2 + r] = xin[(size_t)t * BATCH * INDIM + (size_t)(b0 + r) * INDIM + j];
        }
        __syncthreads();   // sync1: x ready, h_lds stable

        float a0i = binit.x, a0f = binit.y, a0g = binit.z, a0o = binit.w;
        float a1i = binit.x, a1f = binit.y, a1g = binit.z, a1o = binit.w;

        // x @ W_ih^T partial (this quarter: 4 packed pairs)
#pragma unroll
        for (int i = 0; i < 4; ++i) {
            int j2 = (q4 << 2) + i;
            uint4  w  = Xp4[(j2 << 8) + m];
            float4 xv = x4[j2];
            DECODE_FMA(w.x, w.y, xv.x, xv.y);
            DECODE_FMA(w.z, w.w, xv.z, xv.w);
        }

        // h @ W_hh^T partial (this quarter: 32 packed pairs), weights from L2.
        // index stagger (i + 2*q4) spreads the h4 broadcast reads across
        // disjoint bank quads for the 4 q4 groups -> conflict-free.
#pragma unroll 8
        for (int i = 0; i < 32; ++i) {
            int kk2 = (q4 << 5) + ((i + (q4 << 1)) & 31);
            uint4  w  = Wp4[(kk2 << 8) + m];
            float4 hv = h4[kk2];
            DECODE_FMA(w.x, w.y, hv.x, hv.y);
            DECODE_FMA(w.z, w.w, hv.z, hv.w);
        }

        // reduce the 4 k-quarters (adjacent lanes); all 4 get the total
        a0i += __shfl_xor(a0i, 1); a0i += __shfl_xor(a0i, 2);
        a0f += __shfl_xor(a0f, 1); a0f += __shfl_xor(a0f, 2);
        a0g += __shfl_xor(a0g, 1); a0g += __shfl_xor(a0g, 2);
        a0o += __shfl_xor(a0o, 1); a0o += __shfl_xor(a0o, 2);
        a1i += __shfl_xor(a1i, 1); a1i += __shfl_xor(a1i, 2);
        a1f += __shfl_xor(a1f, 1); a1f += __shfl_xor(a1f, 2);
        a1g += __shfl_xor(a1g, 1); a1g += __shfl_xor(a1g, 2);
        a1o += __shfl_xor(a1o, 1); a1o += __shfl_xor(a1o, 2);

        // LSTM cell update, redundantly on all 4 q4 threads (no divergence)
        float i0 = sigf(a0i), f0 = sigf(a0f), g0 = tanhf_(a0g), o0 = sigf(a0o);
        float i1 = sigf(a1i), f1 = sigf(a1f), g1 = tanhf_(a1g), o1 = sigf(a1o);
        c0 = f0 * c0 + i0 * g0;
        c1 = f1 * c1 + i1 * g1;
        float h0 = o0 * tanhf_(c0);
        float h1 = o1 * tanhf_(c1);

        __syncthreads();   // sync2: all reads of old h done
        if (q4 == 0)
            ((float2*)h_lds)[m] = make_float2(h0, h1);
        __syncthreads();   // sync3: new h visible

        // output projection: item = (r,o), 16 lanes x 16-elem partial dots.
        // h_lds banks: 2*sub + r (16 distinct, 4-way broadcast) -> conflict-free.
        {
            float s = 0.0f;
#pragma unroll
            for (int j = 0; j < 16; ++j) {
                int kk = (j << 4) + sub;
                s = __builtin_fmaf(h_lds[(kk << 1) + r_], wot_lds[o_ * 264 + kk], s);
            }
            s += __shfl_xor(s, 1);
            s += __shfl_xor(s, 2);
            s += __shfl_xor(s, 4);
            s += __shfl_xor(s, 8);
            if (sub == 0) {
                float rp = s + bo_;
                size_t iob = (size_t)(b0 + r_) * TSTEPS * ODIM + (size_t)t * ODIM + o_;
                float  ph  = phys[(size_t)t * BATCH * ODIM + (size_t)(b0 + r_) * ODIM + o_];
                outFull[iob] = ph + rp;
                outRnn[iob]  = rp;
            }
        }
    }
#undef DECODE_FMA
}

extern "C" void kernel_launch(void* const* d_in, const int* in_sizes, int n_in,
                              void* d_out, int out_size, void* d_ws, size_t ws_size,
                              hipStream_t stream) {
    const float* xin   = (const float*)d_in[0];
    const float* phys  = (const float*)d_in[1];
    const float* W_ih  = (const float*)d_in[2];
    const float* W_hh  = (const float*)d_in[3];
    const float* b_ih  = (const float*)d_in[4];
    const float* b_hh  = (const float*)d_in[5];
    const float* W_out = (const float*)d_in[6];
    const float* b_out = (const float*)d_in[7];

    char* ws = (char*)d_ws;
    u16*   Wp  = (u16*)ws;
    u16*   Xp  = (u16*)(ws + WS_XP);
    float* Bp  = (float*)(ws + WS_BP);

    prepack_kernel<<<256, 256, 0, stream>>>(W_ih, W_hh, b_ih, b_hh, Wp, Xp, Bp);
    lstm_kernel<<<256, 1024, 0, stream>>>(xin, phys, Wp, Xp, Bp, W_out, b_out, (float*)d_out);
}

// Round 5
// 14469.843 us; speedup vs baseline: 1.7127x; 1.2600x over previous
//
#include <hip/hip_runtime.h>
#include <hip/hip_bf16.h>
#include <stdint.h>

typedef unsigned short u16;
typedef __attribute__((ext_vector_type(8))) _Float16 f16x8;
typedef __attribute__((ext_vector_type(4))) float f32x4;

#define TSTEPS 1024
#define BATCH  512
#define INDIM  32
#define HID    256
#define ODIM   32
#define NCH    66      // 64 gate chunks + 2 projection chunks
#define KCH    9       // 8 h k-chunks + 1 x k-chunk

// workspace: Wb u16[66*9*64*8] = 608256 B @0 ; Bc float[1024] @608256
#define WS_BC (NCH*KCH*64*8*2)

#define MFMA(a,b,c) __builtin_amdgcn_mfma_f32_16x16x32_f16((a),(b),(c),0,0,0)

__device__ __forceinline__ u16 f2h(float v){ _Float16 h=(_Float16)v; return *(u16*)&h; }
__device__ __forceinline__ float sigf(float x){ return 1.0f/(1.0f+__expf(-x)); }
__device__ __forceinline__ float tanhf_(float x){
    float ax=fabsf(x); float e=__expf(-2.f*ax); float t=(1.f-e)/(1.f+e); return copysignf(t,x);
}

// Pack weights into MFMA B-fragment order (fp16):
// Wb[((c*9+kc)*64+lane)*8+j] = B[k][n] = W_cat[n][k]
//   gate chunks c<64: gate g = c>>4, unit m = (c&15)*16 + (lane&15)
//                     -> W_cat row n corresponds to (g, m): W[(g*256+m)][k]
//   proj chunks c=64,65: output o = (c-64)*16 + (lane&15), W_out[o][k] (x-part zero)
//   k = kc*32 + (lane>>4)*8 + j  (kc<8: h-part; kc==8: x-part)
__global__ __launch_bounds__(256) void prepack_kernel(
    const float* __restrict__ W_ih, const float* __restrict__ W_hh,
    const float* __restrict__ b_ih, const float* __restrict__ b_hh,
    const float* __restrict__ W_out,
    u16* __restrict__ Wb, float* __restrict__ Bc)
{
    int tid = blockIdx.x*blockDim.x + threadIdx.x;
    int stride = gridDim.x*blockDim.x;
    const int TOT = NCH*KCH*64*8;
    for (int idx = tid; idx < TOT; idx += stride) {
        int j    = idx & 7;
        int lane = (idx >> 3) & 63;
        int ck   = idx >> 9;          // c*9 + kc
        int kc   = ck % KCH;
        int c    = ck / KCH;
        int kl   = ((lane >> 4) << 3) + j;   // 0..31 within k-chunk
        float v;
        if (c < 64) {
            int g = c >> 4;
            int m = (c & 15) * 16 + (lane & 15);
            if (kc < 8) v = W_hh[(g*HID + m)*HID + (kc*32 + kl)];
            else        v = W_ih[(g*HID + m)*INDIM + kl];
        } else {
            int o = ((c - 64) << 4) + (lane & 15);
            v = (kc < 8) ? W_out[o*HID + kc*32 + kl] : 0.f;
        }
        Wb[idx] = f2h(v);
    }
    // Bc[c*16+q] = bias(gate c>>4, unit (c&15)*16+q)
    for (int n = tid; n < 1024; n += stride) {
        int c = n >> 4, q = n & 15;
        int g = c >> 4;
        int m = (c & 15) * 16 + q;
        Bc[n] = b_ih[g*HID + m] + b_hh[g*HID + m];
    }
}

// 32 blocks x 16 batch rows; 1024 threads = 16 waves.
// wave wv owns chunks {wv, wv+16, wv+32, wv+48} = gates i,f,g,o of units
// wv*16..wv*16+15 -> cell update is fully lane-local (no shuffles).
// waves 0/8 additionally run proj chunk 64/65.
__global__ __launch_bounds__(1024) void lstm_kernel(
    const float* __restrict__ xin,   // [T][B][32]
    const float* __restrict__ phys,  // [T][B][32]
    const u16*  __restrict__ Wb_,    // fragment-packed weights (fp16)
    const float* __restrict__ Bc,    // [1024] combined gate bias
    const float* __restrict__ b_out, // [32]
    float* __restrict__ out)         // [2][B][T][32]
{
    const int tid  = threadIdx.x;
    const int lane = tid & 63;
    const int wv   = tid >> 6;
    const int b0   = blockIdx.x << 4;

    // A-fragments (h_{t-1} | x_t) in fp16, double buffered, fragment-linear
    __shared__ __align__(16) u16 ha[2*KCH*64*8];   // 18432 B

    const f16x8* Wb8 = (const f16x8*)Wb_;
    f16x8* ha8 = (f16x8*)ha;

    const int c0=wv, c1=wv+16, c2=wv+32, c3=wv+48;
    const bool isP = (wv==0) || (wv==8);
    const int  cp  = (wv==0) ? 64 : 65;

    const float bi0 = Bc[(c0<<4)+(lane&15)];   // gate i bias, unit uw
    const float bi1 = Bc[(c1<<4)+(lane&15)];   // gate f
    const float bi2 = Bc[(c2<<4)+(lane&15)];   // gate g
    const float bi3 = Bc[(c3<<4)+(lane&15)];   // gate o
    const int   o_  = ((cp-64)<<4)+(lane&15);
    const float bip = isP ? b_out[o_] : 0.f;

    // this lane's unit for the cell update
    const int uw = (wv << 4) + (lane & 15);

    // x staging duty: waves 4-7 and 12-15 (512 threads)
    const bool useX = ((wv>=4)&&(wv<8)) || (wv>=12);
    const int  s    = (wv<8) ? (tid-256) : (tid-512);   // 0..511
    const int  xrow = s >> 5, xj = s & 31;
    const int  xslot = 8*512 + (xrow + 16*(xj>>3))*8 + (xj&7); // kc==8 region

    float cst0=0.f, cst1=0.f, cst2=0.f, cst3=0.f;   // c-state for rows 4*(lane>>4)+0..3
    float xr_cur=0.f, xr_nxt=0.f;
    float ph0=0.f, ph1=0.f, ph2=0.f, ph3=0.f;

    // zero h-part of buffer 0 (u16 [0..4096) = 2048 u32)
    {
        uint32_t* z = (uint32_t*)ha;
        for (int i = tid; i < 2048; i += 1024) z[i] = 0u;
    }
    if (useX) {
        float x0 = xin[(size_t)(b0+xrow)*INDIM + xj];
        ha[xslot] = f2h(x0);
        xr_cur = xin[(size_t)1*BATCH*INDIM + (size_t)(b0+xrow)*INDIM + xj];
        xr_nxt = xin[(size_t)2*BATCH*INDIM + (size_t)(b0+xrow)*INDIM + xj];
    }

    float* outFull = out;
    float* outRnn  = out + (size_t)BATCH*TSTEPS*ODIM;

    for (int t = 0; t < TSTEPS; ++t) {
        __syncthreads();   // ha[t&1] (h_{t-1}, x_t) complete
        const int bufp = t & 1;
        const int bufn = (t+1) & 1;
        const f16x8* A = ha8 + bufp*(KCH*64);

        // prefetch x_{t+3} into regs (written to LDS two steps later)
        float xr_new = 0.f;
        if (useX) {
            int tt = t+3; if (tt > TSTEPS-1) tt = TSTEPS-1;
            xr_new = xin[(size_t)tt*BATCH*INDIM + (size_t)(b0+xrow)*INDIM + xj];
        }

        // projection of h_{t-1} -> outputs for step t-1 (waves 0,8)
        if (isP) {
            if (t > 0) {
                f32x4 pa = {bip,bip,bip,bip};
#pragma unroll
                for (int kc = 0; kc < KCH; ++kc)
                    pa = MFMA(A[kc*64+lane], Wb8[(cp*KCH+kc)*64+lane], pa);
                int tq = t-1;
#pragma unroll
                for (int r = 0; r < 4; ++r) {
                    int row = ((lane>>4)<<2) + r;
                    float ph = (r==0)?ph0:(r==1)?ph1:(r==2)?ph2:ph3;
                    size_t ob = (size_t)(b0+row)*TSTEPS*ODIM + (size_t)tq*ODIM + o_;
                    outFull[ob] = ph + pa[r];
                    outRnn[ob]  = pa[r];
                }
            }
            // load phys(t) for use at step t+1
#pragma unroll
            for (int r = 0; r < 4; ++r) {
                int row = ((lane>>4)<<2) + r;
                float v = phys[(size_t)t*BATCH*ODIM + (size_t)(b0+row)*ODIM + o_];
                if (r==0) ph0=v; else if (r==1) ph1=v; else if (r==2) ph2=v; else ph3=v;
            }
        }

        // gates: a0=i, a1=f, a2=g, a3=o for unit uw, rows 4*(lane>>4)+r
        f32x4 a0={bi0,bi0,bi0,bi0}, a1={bi1,bi1,bi1,bi1};
        f32x4 a2={bi2,bi2,bi2,bi2}, a3={bi3,bi3,bi3,bi3};
#pragma unroll
        for (int kc = 0; kc < KCH; ++kc) {
            f16x8 af = A[kc*64+lane];
            a0 = MFMA(af, Wb8[(c0*KCH+kc)*64+lane], a0);
            a1 = MFMA(af, Wb8[(c1*KCH+kc)*64+lane], a1);
            a2 = MFMA(af, Wb8[(c2*KCH+kc)*64+lane], a2);
            a3 = MFMA(af, Wb8[(c3*KCH+kc)*64+lane], a3);
        }

        // cell update: fully lane-local; write h_t -> ha[bufn]
#pragma unroll
        for (int r = 0; r < 4; ++r) {
            float gi = sigf(a0[r]);
            float gf = sigf(a1[r]);
            float gg = tanhf_(a2[r]);
            float go = sigf(a3[r]);
            float cs = (r==0)?cst0:(r==1)?cst1:(r==2)?cst2:cst3;
            cs = gf*cs + gi*gg;
            if (r==0) cst0=cs; else if (r==1) cst1=cs; else if (r==2) cst2=cs; else cst3=cs;
            float hv = go*tanhf_(cs);
            int m_r = ((lane>>4)<<2) + r;   // batch row within tile
            ha[bufn*4608 + ((uw>>5)<<9) + (m_r + 16*((uw>>3)&3))*8 + (uw&7)] = f2h(hv);
        }

        // stage x_{t+1} into ha[bufn] and shift the prefetch pipeline
        if (useX) {
            ha[bufn*4608 + xslot] = f2h(xr_cur);
            xr_cur = xr_nxt;
            xr_nxt = xr_new;
        }
    }

    // final projection: rnn_pred(1023) from h_1023 (in buffer 0)
    __syncthreads();
    if (isP) {
        const f16x8* A = ha8;   // buffer (1024)&1 == 0
        f32x4 pa = {bip,bip,bip,bip};
#pragma unroll
        for (int kc = 0; kc < KCH; ++kc)
            pa = MFMA(A[kc*64+lane], Wb8[(cp*KCH+kc)*64+lane], pa);
#pragma unroll
        for (int r = 0; r < 4; ++r) {
            int row = ((lane>>4)<<2) + r;
            float ph = (r==0)?ph0:(r==1)?ph1:(r==2)?ph2:ph3;  // phys(1023)
            size_t ob = (size_t)(b0+row)*TSTEPS*ODIM + (size_t)1023*ODIM + o_;
            outFull[ob] = ph + pa[r];
            outRnn[ob]  = pa[r];
        }
    }
}

extern "C" void kernel_launch(void* const* d_in, const int* in_sizes, int n_in,
                              void* d_out, int out_size, void* d_ws, size_t ws_size,
                              hipStream_t stream) {
    const float* xin   = (const float*)d_in[0];
    const float* phys  = (const float*)d_in[1];
    const float* W_ih  = (const float*)d_in[2];
    const float* W_hh  = (const float*)d_in[3];
    const float* b_ih  = (const float*)d_in[4];
    const float* b_hh  = (const float*)d_in[5];
    const float* W_out = (const float*)d_in[6];
    const float* b_out = (const float*)d_in[7];

    char*  ws = (char*)d_ws;
    u16*   Wb = (u16*)ws;
    float* Bc = (float*)(ws + WS_BC);

    prepack_kernel<<<256, 256, 0, stream>>>(W_ih, W_hh, b_ih, b_hh, W_out, Wb, Bc);
    lstm_kernel<<<32, 1024, 0, stream>>>(xin, phys, Wb, Bc, b_out, (float*)d_out);
}

// Round 6
// 4076.676 us; speedup vs baseline: 6.0791x; 3.5494x over previous
//
#include <hip/hip_runtime.h>
#include <hip/hip_bf16.h>
#include <stdint.h>

typedef unsigned short u16;
typedef __attribute__((ext_vector_type(8))) _Float16 f16x8;
typedef __attribute__((ext_vector_type(4))) float f32x4;

#define TSTEPS 1024
#define BATCH  512
#define INDIM  32
#define HID    256
#define ODIM   32
#define NCH    66      // 64 gate chunks + 2 projection chunks
#define KCH    9       // 8 h k-chunks + 1 x k-chunk

// ---------------- workspace layout (bytes) ----------------
// Wb    u16[66*9*64*8]            @ 0        (608256)
// Bc    float[1024]               @ 608256   (4096)
// xbuf  u16[32][2][2][2048]       @ 612352   (524288)  h-half exchange
// flags int, [32][2] in 64B slots @ 1136640  (4096)
#define WS_BC   (NCH*KCH*64*8*2)
#define WS_XBUF (WS_BC + 4096)
#define WS_FLAG (WS_XBUF + 32*2*2*4096)

#define MFMA(a,b,c) __builtin_amdgcn_mfma_f32_16x16x32_f16((a),(b),(c),0,0,0)

__device__ __forceinline__ u16 f2h(float v){ _Float16 h=(_Float16)v; return *(u16*)&h; }
__device__ __forceinline__ float sigf(float x){ return 1.0f/(1.0f+__expf(-x)); }
__device__ __forceinline__ float tanhf_(float x){
    float ax=fabsf(x); float e=__expf(-2.f*ax); float t=(1.f-e)/(1.f+e); return copysignf(t,x);
}

// Pack weights into MFMA B-fragment order (fp16) — same as R5:
// gate chunks c<64: gate g=c>>4, unit m=(c&15)*16+(lane&15); proj c=64,65: W_out
// k = kc*32 + (lane>>4)*8 + j (kc<8: h; kc==8: x)
__global__ __launch_bounds__(256) void prepack_kernel(
    const float* __restrict__ W_ih, const float* __restrict__ W_hh,
    const float* __restrict__ b_ih, const float* __restrict__ b_hh,
    const float* __restrict__ W_out,
    u16* __restrict__ Wb, float* __restrict__ Bc)
{
    int tid = blockIdx.x*blockDim.x + threadIdx.x;
    int stride = gridDim.x*blockDim.x;
    const int TOT = NCH*KCH*64*8;
    for (int idx = tid; idx < TOT; idx += stride) {
        int j    = idx & 7;
        int lane = (idx >> 3) & 63;
        int ck   = idx >> 9;
        int kc   = ck % KCH;
        int c    = ck / KCH;
        int kl   = ((lane >> 4) << 3) + j;
        float v;
        if (c < 64) {
            int g = c >> 4;
            int m = (c & 15) * 16 + (lane & 15);
            if (kc < 8) v = W_hh[(g*HID + m)*HID + (kc*32 + kl)];
            else        v = W_ih[(g*HID + m)*INDIM + kl];
        } else {
            int o = ((c - 64) << 4) + (lane & 15);
            v = (kc < 8) ? W_out[o*HID + kc*32 + kl] : 0.f;
        }
        Wb[idx] = f2h(v);
    }
    for (int n = tid; n < 1024; n += stride) {
        int c = n >> 4, q = n & 15;
        int g = c >> 4;
        int m = (c & 15) * 16 + q;
        Bc[n] = b_ih[g*HID + m] + b_hh[g*HID + m];
    }
}

__global__ __launch_bounds__(1024) void zero_flags_kernel(int* __restrict__ flags) {
    flags[threadIdx.x] = 0;   // 4096 B
}

// 64 blocks x 512 threads (8 waves). Pair (tile) = blocks {b, b+8}:
// hf = (bid>>3)&1, tile = (bid&7) | ((bid>>4)<<3). Block owns units
// hf*128..hf*128+127; wave wv owns unit group ug = hf*8+wv (16 units, all 4 gates,
// lane-local cell update). All 36 gate B-fragments live in VGPRs.
// Per step: blocks exchange 4KB h-halves via xbuf + release/acquire flags.
__global__ __launch_bounds__(512) void lstm_kernel(
    const float* __restrict__ xin,   // [T][B][32]
    const float* __restrict__ phys,  // [T][B][32]
    const u16*  __restrict__ Wb_,    // fragment-packed weights (fp16)
    const float* __restrict__ Bc,    // [1024] combined gate bias
    const float* __restrict__ b_out, // [32]
    u16* __restrict__ xbuf,          // exchange buffers
    int* __restrict__ flags,         // progress flags
    float* __restrict__ out)         // [2][B][T][32]
{
    const int tid  = threadIdx.x;
    const int lane = tid & 63;
    const int wv   = tid >> 6;                    // 0..7
    const int bid  = blockIdx.x;
    const int hf   = (bid >> 3) & 1;
    const int phf  = 1 - hf;
    const int tile = (bid & 7) | ((bid >> 4) << 3);
    const int b0   = tile << 4;

    __shared__ __align__(16) u16 ha[2*KCH*64*8];  // 18432 B, double buffered

    const f16x8* Wb8 = (const f16x8*)Wb_;
    f16x8* ha8 = (f16x8*)ha;

    const int ug = hf*8 + wv;                     // unit group 0..15
    const int uw = (ug << 4) + (lane & 15);       // this lane's unit

    const float bi0 = Bc[((0*16+ug)<<4)+(lane&15)];
    const float bi1 = Bc[((1*16+ug)<<4)+(lane&15)];
    const float bi2 = Bc[((2*16+ug)<<4)+(lane&15)];
    const float bi3 = Bc[((3*16+ug)<<4)+(lane&15)];

    const bool  isP = (wv == 0);                  // one proj wave per block
    const int   cp  = 64 + hf;                    // proj chunk: o 0..15 / 16..31
    const int   o_  = (hf << 4) + (lane & 15);
    const float bip = isP ? b_out[o_] : 0.f;

    // ---- load the 36 gate B-fragments into registers (once) ----
    f16x8 wOwn[4][5];   // own-half h kcs (4) + x kc (idx 4)
    f16x8 wPar[4][4];   // partner-half h kcs
#pragma unroll
    for (int g = 0; g < 4; ++g) {
        const int cg = g*16 + ug;
#pragma unroll
        for (int i = 0; i < 4; ++i)
            wOwn[g][i] = Wb8[(cg*KCH + (4*hf+i))*64 + lane];
        wOwn[g][4] = Wb8[(cg*KCH + 8)*64 + lane];
#pragma unroll
        for (int i = 0; i < 4; ++i)
            wPar[g][i] = Wb8[(cg*KCH + (4*phf+i))*64 + lane];
    }

    // x staging: each of 512 threads owns one (row, j)
    const int xrow  = tid >> 5, xj = tid & 31;
    const int xslot = 4096 + (xrow + 16*(xj>>3))*8 + (xj&7);

    // h write slot bases
    const int mr_base = (lane >> 4) << 2;
    const int hlocal  = ((uw>>5)<<9) + (16*((uw>>3)&3))*8 + (uw&7);      // + mr*8
    const int hx      = (((uw>>5)&3)<<9) + (16*((uw>>3)&3))*8 + (uw&7);  // + mr*8

    float cst0=0.f,cst1=0.f,cst2=0.f,cst3=0.f;
    float ph0=0.f,ph1=0.f,ph2=0.f,ph3=0.f;
    float xr_cur=0.f, xr_nxt=0.f;

    // zero full h region of buffer 0 (4096 u16 = 2048 u32)
    {
        uint32_t* z = (uint32_t*)ha;
#pragma unroll
        for (int i = 0; i < 4; ++i) z[tid + 512*i] = 0u;
    }
    // stage x_0; prefetch x_1, x_2
    ha[xslot] = f2h(xin[(size_t)(b0+xrow)*INDIM + xj]);
    xr_cur = xin[(size_t)1*BATCH*INDIM + (size_t)(b0+xrow)*INDIM + xj];
    xr_nxt = xin[(size_t)2*BATCH*INDIM + (size_t)(b0+xrow)*INDIM + xj];
    __syncthreads();

    const int* pflag = flags + tile*32 + phf*16;  // partner flag (64B slots)
    int*       mflag = flags + tile*32 + hf*16;   // my flag

    float* outFull = out;
    float* outRnn  = out + (size_t)BATCH*TSTEPS*ODIM;

    for (int t = 0; t < TSTEPS; ++t) {
        const int bufp = t & 1;
        const int bufn = bufp ^ 1;
        const f16x8* A = ha8 + bufp*(KCH*64);

        // ---- phase 1: own-half + x gate MFMAs (no partner dependency) ----
        f32x4 a0={bi0,bi0,bi0,bi0}, a1={bi1,bi1,bi1,bi1};
        f32x4 a2={bi2,bi2,bi2,bi2}, a3={bi3,bi3,bi3,bi3};
        {
            f16x8 af = A[8*64+lane];
            a0 = MFMA(af, wOwn[0][4], a0);
            a1 = MFMA(af, wOwn[1][4], a1);
            a2 = MFMA(af, wOwn[2][4], a2);
            a3 = MFMA(af, wOwn[3][4], a3);
        }
#pragma unroll
        for (int i = 0; i < 4; ++i) {
            f16x8 af = A[(4*hf+i)*64+lane];
            a0 = MFMA(af, wOwn[0][i], a0);
            a1 = MFMA(af, wOwn[1][i], a1);
            a2 = MFMA(af, wOwn[2][i], a2);
            a3 = MFMA(af, wOwn[3][i], a3);
        }

        // prefetch x_{t+3}
        float xr_new;
        {
            int tt = t+3; if (tt > TSTEPS-1) tt = TSTEPS-1;
            xr_new = xin[(size_t)tt*BATCH*INDIM + (size_t)(b0+xrow)*INDIM + xj];
        }

        // ---- phase 2: wait partner h_{t-1}, copy into ha[bufp] partner region ----
        if (t > 0) {
            if (wv == 7 && lane == 0) {
                while (__hip_atomic_load(pflag, __ATOMIC_RELAXED, __HIP_MEMORY_SCOPE_AGENT) < t)
                    __builtin_amdgcn_s_sleep(1);
                (void)__hip_atomic_load(pflag, __ATOMIC_ACQUIRE, __HIP_MEMORY_SCOPE_AGENT);
            }
            __syncthreads();   // poll done; caches invalidated on this CU
            const uint2* src = (const uint2*)(xbuf + ((size_t)(tile*2 + bufp)*2 + phf)*2048);
            uint2 v = src[tid];
            *(uint2*)(ha + bufp*4608 + phf*2048 + (size_t)tid*4) = v;
        }
        __syncthreads();       // partner region of ha[bufp] visible

        // ---- phase 3: partner-half gate MFMAs ----
#pragma unroll
        for (int i = 0; i < 4; ++i) {
            f16x8 af = A[(4*phf+i)*64+lane];
            a0 = MFMA(af, wPar[0][i], a0);
            a1 = MFMA(af, wPar[1][i], a1);
            a2 = MFMA(af, wPar[2][i], a2);
            a3 = MFMA(af, wPar[3][i], a3);
        }

        // ---- projection of h_{t-1} (wave 0): outputs step t-1 ----
        if (isP) {
            if (t > 0) {
                f32x4 pa = {bip,bip,bip,bip};
#pragma unroll
                for (int kc = 0; kc < KCH; ++kc)
                    pa = MFMA(A[kc*64+lane], Wb8[(cp*KCH+kc)*64+lane], pa);
                int tq = t-1;
#pragma unroll
                for (int r = 0; r < 4; ++r) {
                    int row = mr_base + r;
                    float ph = (r==0)?ph0:(r==1)?ph1:(r==2)?ph2:ph3;
                    size_t ob = (size_t)(b0+row)*TSTEPS*ODIM + (size_t)tq*ODIM + o_;
                    outFull[ob] = ph + pa[r];
                    outRnn[ob]  = pa[r];
                }
            }
#pragma unroll
            for (int r = 0; r < 4; ++r) {
                int row = mr_base + r;
                float v = phys[(size_t)t*BATCH*ODIM + (size_t)(b0+row)*ODIM + o_];
                if (r==0) ph0=v; else if (r==1) ph1=v; else if (r==2) ph2=v; else ph3=v;
            }
        }

        // ---- cell update (lane-local) + h writes (LDS + exchange buffer) ----
        u16* xdst = xbuf + ((size_t)(tile*2 + bufn)*2 + hf)*2048;
#pragma unroll
        for (int r = 0; r < 4; ++r) {
            float gi = sigf(a0[r]);
            float gf = sigf(a1[r]);
            float gg = tanhf_(a2[r]);
            float go = sigf(a3[r]);
            float cs = (r==0)?cst0:(r==1)?cst1:(r==2)?cst2:cst3;
            cs = gf*cs + gi*gg;
            if (r==0) cst0=cs; else if (r==1) cst1=cs; else if (r==2) cst2=cs; else cst3=cs;
            float hv = go*tanhf_(cs);
            u16 hb = f2h(hv);
            int mr = mr_base + r;
            ha[bufn*4608 + hlocal + mr*8] = hb;
            xdst[hx + mr*8] = hb;
        }

        // stage x_{t+1}; shift prefetch pipeline
        ha[bufn*4608 + xslot] = f2h(xr_cur);
        xr_cur = xr_nxt;
        xr_nxt = xr_new;

        __syncthreads();   // drains vmcnt/lgkmcnt for ALL waves before flag
        if (wv == 7 && lane == 0)
            __hip_atomic_store(mflag, t+1, __ATOMIC_RELEASE, __HIP_MEMORY_SCOPE_AGENT);
    }

    // ---- final projection: outputs t=1023 from h_1023 (buffer 0) ----
    if (wv == 7 && lane == 0) {
        while (__hip_atomic_load(pflag, __ATOMIC_RELAXED, __HIP_MEMORY_SCOPE_AGENT) < TSTEPS)
            __builtin_amdgcn_s_sleep(1);
        (void)__hip_atomic_load(pflag, __ATOMIC_ACQUIRE, __HIP_MEMORY_SCOPE_AGENT);
    }
    __syncthreads();
    {
        const uint2* src = (const uint2*)(xbuf + ((size_t)(tile*2 + 0)*2 + phf)*2048);
        *(uint2*)(ha + phf*2048 + (size_t)tid*4) = src[tid];
    }
    __syncthreads();
    if (isP) {
        const f16x8* A = ha8;   // parity of h_1023 is 0
        f32x4 pa = {bip,bip,bip,bip};
#pragma unroll
        for (int kc = 0; kc < KCH; ++kc)
            pa = MFMA(A[kc*64+lane], Wb8[(cp*KCH+kc)*64+lane], pa);
#pragma unroll
        for (int r = 0; r < 4; ++r) {
            int row = mr_base + r;
            float ph = (r==0)?ph0:(r==1)?ph1:(r==2)?ph2:ph3;  // phys(1023)
            size_t ob = (size_t)(b0+row)*TSTEPS*ODIM + (size_t)1023*ODIM + o_;
            outFull[ob] = ph + pa[r];
            outRnn[ob]  = pa[r];
        }
    }
}

extern "C" void kernel_launch(void* const* d_in, const int* in_sizes, int n_in,
                              void* d_out, int out_size, void* d_ws, size_t ws_size,
                              hipStream_t stream) {
    const float* xin   = (const float*)d_in[0];
    const float* phys  = (const float*)d_in[1];
    const float* W_ih  = (const float*)d_in[2];
    const float* W_hh  = (const float*)d_in[3];
    const float* b_ih  = (const float*)d_in[4];
    const float* b_hh  = (const float*)d_in[5];
    const float* W_out = (const float*)d_in[6];
    const float* b_out = (const float*)d_in[7];

    char*  ws    = (char*)d_ws;
    u16*   Wb    = (u16*)ws;
    float* Bc    = (float*)(ws + WS_BC);
    u16*   xbuf  = (u16*)(ws + WS_XBUF);
    int*   flags = (int*)(ws + WS_FLAG);

    prepack_kernel<<<256, 256, 0, stream>>>(W_ih, W_hh, b_ih, b_hh, W_out, Wb, Bc);
    zero_flags_kernel<<<1, 1024, 0, stream>>>(flags);
    lstm_kernel<<<64, 512, 0, stream>>>(xin, phys, Wb, Bc, b_out, xbuf, flags, (float*)d_out);
}

// Round 7
// 3704.665 us; speedup vs baseline: 6.6896x; 1.1004x over previous
//
#include <hip/hip_runtime.h>
#include <hip/hip_bf16.h>
#include <stdint.h>

typedef unsigned short u16;
typedef __attribute__((ext_vector_type(8))) _Float16 f16x8;
typedef __attribute__((ext_vector_type(4))) float f32x4;

#define TSTEPS 1024
#define BATCH  512
#define INDIM  32
#define HID    256
#define ODIM   32
#define NCH    66      // 64 gate chunks + 2 projection chunks
#define KCH    9       // 8 h k-chunks + 1 x k-chunk

// ---------------- workspace layout (bytes) ----------------
// Wb    u16[66*9*64*8]            @ 0        (608256)
// Bc    float[1024]               @ 608256   (4096)
// xbuf  u16[32][2][2][2048]       @ 612352   (524288)  h-half exchange (frag order)
// flags int, [32][2] in 64B slots @ 1136640  (4096)
#define WS_BC   (NCH*KCH*64*8*2)
#define WS_XBUF (WS_BC + 4096)
#define WS_FLAG (WS_XBUF + 32*2*2*4096)

#define MFMA(a,b,c) __builtin_amdgcn_mfma_f32_16x16x32_f16((a),(b),(c),0,0,0)

__device__ __forceinline__ u16 f2h(float v){ _Float16 h=(_Float16)v; return *(u16*)&h; }
__device__ __forceinline__ float sigf(float x){ return 1.0f/(1.0f+__expf(-x)); }
__device__ __forceinline__ float tanhf_(float x){
    float ax=fabsf(x); float e=__expf(-2.f*ax); float t=(1.f-e)/(1.f+e); return copysignf(t,x);
}

// Pack weights into MFMA B-fragment order (fp16) — same mapping as R6.
__global__ __launch_bounds__(256) void prepack_kernel(
    const float* __restrict__ W_ih, const float* __restrict__ W_hh,
    const float* __restrict__ b_ih, const float* __restrict__ b_hh,
    const float* __restrict__ W_out,
    u16* __restrict__ Wb, float* __restrict__ Bc)
{
    int tid = blockIdx.x*blockDim.x + threadIdx.x;
    int stride = gridDim.x*blockDim.x;
    const int TOT = NCH*KCH*64*8;
    for (int idx = tid; idx < TOT; idx += stride) {
        int j    = idx & 7;
        int lane = (idx >> 3) & 63;
        int ck   = idx >> 9;
        int kc   = ck % KCH;
        int c    = ck / KCH;
        int kl   = ((lane >> 4) << 3) + j;
        float v;
        if (c < 64) {
            int g = c >> 4;
            int m = (c & 15) * 16 + (lane & 15);
            if (kc < 8) v = W_hh[(g*HID + m)*HID + (kc*32 + kl)];
            else        v = W_ih[(g*HID + m)*INDIM + kl];
        } else {
            int o = ((c - 64) << 4) + (lane & 15);
            v = (kc < 8) ? W_out[o*HID + kc*32 + kl] : 0.f;
        }
        Wb[idx] = f2h(v);
    }
    for (int n = tid; n < 1024; n += stride) {
        int c = n >> 4, q = n & 15;
        int g = c >> 4;
        int m = (c & 15) * 16 + q;
        Bc[n] = b_ih[g*HID + m] + b_hh[g*HID + m];
    }
}

__global__ __launch_bounds__(1024) void zero_flags_kernel(int* __restrict__ flags) {
    flags[threadIdx.x] = 0;
}

// 64 blocks x 512 threads (8 waves). Pair = blocks {b, b+8} (same XCD heuristic):
// hf=(bid>>3)&1, tile=(bid&7)|((bid>>4)<<3). Block owns units hf*128..+127;
// wave wv owns unit group ug=hf*8+wv (16 units x 4 gates, lane-local cell).
// All gate/proj B-fragments register-resident. Partner h read straight from L2.
__global__ __launch_bounds__(512) void lstm_kernel(
    const float* __restrict__ xin,   // [T][B][32]
    const float* __restrict__ phys,  // [T][B][32]
    const u16*  __restrict__ Wb_,
    const float* __restrict__ Bc,
    const float* __restrict__ b_out,
    u16* __restrict__ xbuf,
    int* __restrict__ flags,
    float* __restrict__ out)         // [2][B][T][32]
{
    const int tid  = threadIdx.x;
    const int lane = tid & 63;
    const int wv   = tid >> 6;
    const int bid  = blockIdx.x;
    const int hf   = (bid >> 3) & 1;
    const int phf  = 1 - hf;
    const int tile = (bid & 7) | ((bid >> 4) << 3);
    const int b0   = tile << 4;

    __shared__ __align__(16) u16   ha[2*2048];        // own h-half, double buffered (8KB)
    __shared__ __align__(16) u16   xring[16][512];    // x fragments, 16 steps (16KB)
    __shared__ __align__(16) float physring[16][512]; // phys, 16 steps (32KB)
    __shared__ __align__(16) float outring[8][256];   // rnn_pred, 8 steps (8KB)

    const f16x8* Wb8 = (const f16x8*)Wb_;

    const int ug = hf*8 + wv;
    const int uw = (ug << 4) + (lane & 15);

    const float bi0 = Bc[((0*16+ug)<<4)+(lane&15)];
    const float bi1 = Bc[((1*16+ug)<<4)+(lane&15)];
    const float bi2 = Bc[((2*16+ug)<<4)+(lane&15)];
    const float bi3 = Bc[((3*16+ug)<<4)+(lane&15)];

    const bool  isP = (wv == 0);
    const int   o_  = (hf << 4) + (lane & 15);
    const float bip = b_out[o_];

    // ---- register-resident B-fragments ----
    f16x8 wOwn[4][5];    // 4 gates x (4 own-h kcs + x kc)
    f16x8 wPar[4][4];    // 4 gates x 4 partner-h kcs
    f16x8 wPrO[4];       // projection, own-h kcs
    f16x8 wPrP[4];       // projection, partner-h kcs
#pragma unroll
    for (int g = 0; g < 4; ++g) {
        const int cg = g*16 + ug;
#pragma unroll
        for (int i = 0; i < 4; ++i)
            wOwn[g][i] = Wb8[(cg*KCH + (4*hf+i))*64 + lane];
        wOwn[g][4] = Wb8[(cg*KCH + 8)*64 + lane];
#pragma unroll
        for (int i = 0; i < 4; ++i)
            wPar[g][i] = Wb8[(cg*KCH + (4*phf+i))*64 + lane];
    }
#pragma unroll
    for (int i = 0; i < 4; ++i) {
        wPrO[i] = Wb8[((64+hf)*KCH + (4*hf+i))*64 + lane];
        wPrP[i] = Wb8[((64+hf)*KCH + (4*phf+i))*64 + lane];
    }

    const int xrow = tid >> 5, xj = tid & 31;
    const int xfs  = (xrow + 16*(xj>>3))*8 + (xj&7);   // fragment slot in a 512-u16 tile
    const int mr_base = (lane >> 4) << 2;
    const int ul  = uw - hf*128;                        // unit index within own half
    const int hx  = ((ul>>5)<<9) + (16*((ul>>3)&3))*8 + (ul&7);  // + mr*8

    float cst0=0.f,cst1=0.f,cst2=0.f,cst3=0.f;

    // ---- init: zero ha buf0, preload x/phys rings for steps 0..15 ----
    ((uint32_t*)ha)[tid] = 0u;
    ((uint32_t*)ha)[tid + 512] = 0u;
#pragma unroll 4
    for (int s = 0; s < 16; ++s) {
        xring[s][xfs]   = f2h(xin[(size_t)s*BATCH*INDIM + (size_t)b0*INDIM + tid]);
        physring[s][tid] = phys[(size_t)s*BATCH*ODIM + (size_t)b0*ODIM + tid];
    }
    __syncthreads();

    const int* pflag = flags + tile*32 + phf*16;
    int*       mflag = flags + tile*32 + hf*16;

    float* outFull = out;
    float* outRnn  = out + (size_t)BATCH*TSTEPS*ODIM;

    for (int t = 0; t < TSTEPS; ++t) {
        const int bufp = t & 1;
        const int bufn = bufp ^ 1;
        const f16x8* A = (const f16x8*)(ha + bufp*2048);

        // ---- phase 1: x + own-half gate MFMAs; wave0 also proj(own) of h_{t-1} ----
        f32x4 a0={bi0,bi0,bi0,bi0}, a1={bi1,bi1,bi1,bi1};
        f32x4 a2={bi2,bi2,bi2,bi2}, a3={bi3,bi3,bi3,bi3};
        {
            f16x8 afx = ((const f16x8*)xring)[(t&15)*64 + lane];
            a0 = MFMA(afx, wOwn[0][4], a0);
            a1 = MFMA(afx, wOwn[1][4], a1);
            a2 = MFMA(afx, wOwn[2][4], a2);
            a3 = MFMA(afx, wOwn[3][4], a3);
        }
        f16x8 afO0 = A[0*64+lane], afO1 = A[1*64+lane];
        f16x8 afO2 = A[2*64+lane], afO3 = A[3*64+lane];
        a0=MFMA(afO0,wOwn[0][0],a0); a1=MFMA(afO0,wOwn[1][0],a1); a2=MFMA(afO0,wOwn[2][0],a2); a3=MFMA(afO0,wOwn[3][0],a3);
        a0=MFMA(afO1,wOwn[0][1],a0); a1=MFMA(afO1,wOwn[1][1],a1); a2=MFMA(afO1,wOwn[2][1],a2); a3=MFMA(afO1,wOwn[3][1],a3);
        a0=MFMA(afO2,wOwn[0][2],a0); a1=MFMA(afO2,wOwn[1][2],a1); a2=MFMA(afO2,wOwn[2][2],a2); a3=MFMA(afO2,wOwn[3][2],a3);
        a0=MFMA(afO3,wOwn[0][3],a0); a1=MFMA(afO3,wOwn[1][3],a1); a2=MFMA(afO3,wOwn[2][3],a2); a3=MFMA(afO3,wOwn[3][3],a3);

        f32x4 pa = {bip,bip,bip,bip};
        if (isP && t > 0) {
            pa = MFMA(afO0, wPrO[0], pa);
            pa = MFMA(afO1, wPrO[1], pa);
            pa = MFMA(afO2, wPrO[2], pa);
            pa = MFMA(afO3, wPrO[3], pa);
        }

        // ---- wait partner h_{t-1} published ----
        if (t > 0 && wv == 7 && lane == 0) {
            while (__hip_atomic_load(pflag, __ATOMIC_RELAXED, __HIP_MEMORY_SCOPE_AGENT) < t)
                __builtin_amdgcn_s_sleep(1);
            (void)__hip_atomic_load(pflag, __ATOMIC_ACQUIRE, __HIP_MEMORY_SCOPE_AGENT);
        }
        __syncthreads();   // barrier C

        // ---- phase 3: partner-half gate MFMAs straight from L2; wave0 proj(partner) ----
        if (t > 0) {
            const f16x8* xbG = (const f16x8*)(xbuf + ((size_t)(tile*2 + bufp)*2 + phf)*2048);
            f16x8 afP0 = xbG[0*64+lane], afP1 = xbG[1*64+lane];
            f16x8 afP2 = xbG[2*64+lane], afP3 = xbG[3*64+lane];
            a0=MFMA(afP0,wPar[0][0],a0); a1=MFMA(afP0,wPar[1][0],a1); a2=MFMA(afP0,wPar[2][0],a2); a3=MFMA(afP0,wPar[3][0],a3);
            a0=MFMA(afP1,wPar[0][1],a0); a1=MFMA(afP1,wPar[1][1],a1); a2=MFMA(afP1,wPar[2][1],a2); a3=MFMA(afP1,wPar[3][1],a3);
            a0=MFMA(afP2,wPar[0][2],a0); a1=MFMA(afP2,wPar[1][2],a1); a2=MFMA(afP2,wPar[2][2],a2); a3=MFMA(afP2,wPar[3][2],a3);
            a0=MFMA(afP3,wPar[0][3],a0); a1=MFMA(afP3,wPar[1][3],a1); a2=MFMA(afP3,wPar[2][3],a2); a3=MFMA(afP3,wPar[3][3],a3);
            if (isP) {
                pa = MFMA(afP0, wPrP[0], pa);
                pa = MFMA(afP1, wPrP[1], pa);
                pa = MFMA(afP2, wPrP[2], pa);
                pa = MFMA(afP3, wPrP[3], pa);
                const int os = (t-1) & 7;
#pragma unroll
                for (int r = 0; r < 4; ++r)
                    outring[os][(mr_base+r)*16 + (lane&15)] = pa[r];
            }
        }

        // ---- cell update (lane-local) + h_t stores (LDS own + L2 exchange) ----
        u16* xdst = xbuf + ((size_t)(tile*2 + bufn)*2 + hf)*2048;
#pragma unroll
        for (int r = 0; r < 4; ++r) {
            float gi = sigf(a0[r]);
            float gf = sigf(a1[r]);
            float gg = tanhf_(a2[r]);
            float go = sigf(a3[r]);
            float cs = (r==0)?cst0:(r==1)?cst1:(r==2)?cst2:cst3;
            cs = gf*cs + gi*gg;
            if (r==0) cst0=cs; else if (r==1) cst1=cs; else if (r==2) cst2=cs; else cst3=cs;
            float hv = go*tanhf_(cs);
            u16 hb = f2h(hv);
            int mr = mr_base + r;
            ha[bufn*2048 + hx + mr*8] = hb;
            xdst[hx + mr*8] = hb;
        }

        __syncthreads();   // barrier D: all h stores drained
        if (wv == 7 && lane == 0)
            __hip_atomic_store(mflag, t+1, __ATOMIC_RELEASE, __HIP_MEMORY_SCOPE_AGENT);

        // ---- every 8 steps: flush outputs, reload x/phys rings (off critical path) ----
        if ((t & 7) == 0 && t > 0) {
            const int tb = t - 8;
#pragma unroll
            for (int k = 0; k < 4; ++k) {
                int e   = tid + (k << 9);
                int s   = e >> 8;
                int rem = e & 255;
                int row = rem >> 4, oq = rem & 15;
                int sa  = tb + s;
                float rnn = outring[s][row*16 + oq];
                float ph  = physring[sa & 15][row*32 + (hf<<4) + oq];
                size_t ob = (size_t)(b0+row)*TSTEPS*ODIM + (size_t)sa*ODIM + ((hf<<4)+oq);
                outFull[ob] = ph + rnn;
                outRnn [ob] = rnn;
            }
            __syncthreads();   // flush reads done before ring overwrite
            if (t + 8 < TSTEPS) {
#pragma unroll 2
                for (int s = 0; s < 8; ++s) {
                    int ts = t + 8 + s;
                    xring[ts & 15][xfs]   = f2h(xin[(size_t)ts*BATCH*INDIM + (size_t)b0*INDIM + tid]);
                    physring[ts & 15][tid] = phys[(size_t)ts*BATCH*ODIM + (size_t)b0*ODIM + tid];
                }
            }
        }
    }

    // ---- epilogue: rnn(1023) from h_1023 (parity 0), then flush steps 1016..1023 ----
    if (wv == 7 && lane == 0) {
        while (__hip_atomic_load(pflag, __ATOMIC_RELAXED, __HIP_MEMORY_SCOPE_AGENT) < TSTEPS)
            __builtin_amdgcn_s_sleep(1);
        (void)__hip_atomic_load(pflag, __ATOMIC_ACQUIRE, __HIP_MEMORY_SCOPE_AGENT);
    }
    __syncthreads();
    if (isP) {
        const f16x8* A = (const f16x8*)ha;   // h_1023 own half (parity 0)
        f16x8 aO0 = A[0*64+lane], aO1 = A[1*64+lane], aO2 = A[2*64+lane], aO3 = A[3*64+lane];
        const f16x8* xbG = (const f16x8*)(xbuf + ((size_t)(tile*2 + 0)*2 + phf)*2048);
        f16x8 aP0 = xbG[0*64+lane], aP1 = xbG[1*64+lane], aP2 = xbG[2*64+lane], aP3 = xbG[3*64+lane];
        f32x4 pa = {bip,bip,bip,bip};
        pa = MFMA(aO0, wPrO[0], pa); pa = MFMA(aO1, wPrO[1], pa);
        pa = MFMA(aO2, wPrO[2], pa); pa = MFMA(aO3, wPrO[3], pa);
        pa = MFMA(aP0, wPrP[0], pa); pa = MFMA(aP1, wPrP[1], pa);
        pa = MFMA(aP2, wPrP[2], pa); pa = MFMA(aP3, wPrP[3], pa);
#pragma unroll
        for (int r = 0; r < 4; ++r)
            outring[7][(mr_base+r)*16 + (lane&15)] = pa[r];
    }
    __syncthreads();
#pragma unroll
    for (int k = 0; k < 4; ++k) {
        int e   = tid + (k << 9);
        int s   = e >> 8;
        int rem = e & 255;
        int row = rem >> 4, oq = rem & 15;
        int sa  = 1016 + s;
        float rnn = outring[s][row*16 + oq];
        float ph  = physring[sa & 15][row*32 + (hf<<4) + oq];
        size_t ob = (size_t)(b0+row)*TSTEPS*ODIM + (size_t)sa*ODIM + ((hf<<4)+oq);
        outFull[ob] = ph + rnn;
        outRnn [ob] = rnn;
    }
}

extern "C" void kernel_launch(void* const* d_in, const int* in_sizes, int n_in,
                              void* d_out, int out_size, void* d_ws, size_t ws_size,
                              hipStream_t stream) {
    const float* xin   = (const float*)d_in[0];
    const float* phys  = (const float*)d_in[1];
    const float* W_ih  = (const float*)d_in[2];
    const float* W_hh  = (const float*)d_in[3];
    const float* b_ih  = (const float*)d_in[4];
    const float* b_hh  = (const float*)d_in[5];
    const float* W_out = (const float*)d_in[6];
    const float* b_out = (const float*)d_in[7];

    char*  ws    = (char*)d_ws;
    u16*   Wb    = (u16*)ws;
    float* Bc    = (float*)(ws + WS_BC);
    u16*   xbuf  = (u16*)(ws + WS_XBUF);
    int*   flags = (int*)(ws + WS_FLAG);

    prepack_kernel<<<256, 256, 0, stream>>>(W_ih, W_hh, b_ih, b_hh, W_out, Wb, Bc);
    zero_flags_kernel<<<1, 1024, 0, stream>>>(flags);
    lstm_kernel<<<64, 512, 0, stream>>>(xin, phys, Wb, Bc, b_out, xbuf, flags, (float*)d_out);
}

// Round 8
// 2864.440 us; speedup vs baseline: 8.6519x; 1.2933x over previous
//
#include <hip/hip_runtime.h>
#include <hip/hip_bf16.h>
#include <stdint.h>

typedef unsigned short u16;
typedef unsigned long long u64;
typedef __attribute__((ext_vector_type(8))) _Float16 f16x8;
typedef __attribute__((ext_vector_type(4))) float f32x4;

#define TSTEPS 1024
#define BATCH  512
#define INDIM  32
#define HID    256
#define ODIM   32
#define NCH    66      // 64 gate chunks + 2 projection chunks
#define KCH    9       // 8 h k-chunks + 1 x k-chunk

// ---------------- workspace layout (bytes) ----------------
// Wb    u16[66*9*64*8]            @ 0        (608256)
// Bc    float[1024]               @ 608256   (4096)
// xbuf  u16[32][2][2][2048]       @ 612352   (524288)  h-half exchange (frag order)
// flags int, [32][2] in 64B slots @ 1136640  (4096)
#define WS_BC   (NCH*KCH*64*8*2)
#define WS_XBUF (WS_BC + 4096)
#define WS_FLAG (WS_XBUF + 32*2*2*4096)

#define MFMA(a,b,c) __builtin_amdgcn_mfma_f32_16x16x32_f16((a),(b),(c),0,0,0)

__device__ __forceinline__ u16 f2h(float v){ _Float16 h=(_Float16)v; return *(u16*)&h; }
__device__ __forceinline__ float sigf(float x){ return 1.0f/(1.0f+__expf(-x)); }
__device__ __forceinline__ float tanhf_(float x){
    float ax=fabsf(x); float e=__expf(-2.f*ax); float t=(1.f-e)/(1.f+e); return copysignf(t,x);
}
__device__ __forceinline__ f16x8 frag_from_u64(u64 lo, u64 hi){
    union { u64 q[2]; f16x8 v; } u;
    u.q[0] = lo; u.q[1] = hi;
    return u.v;
}

// Pack weights into MFMA B-fragment order (fp16) — same mapping as R7.
__global__ __launch_bounds__(256) void prepack_kernel(
    const float* __restrict__ W_ih, const float* __restrict__ W_hh,
    const float* __restrict__ b_ih, const float* __restrict__ b_hh,
    const float* __restrict__ W_out,
    u16* __restrict__ Wb, float* __restrict__ Bc)
{
    int tid = blockIdx.x*blockDim.x + threadIdx.x;
    int stride = gridDim.x*blockDim.x;
    const int TOT = NCH*KCH*64*8;
    for (int idx = tid; idx < TOT; idx += stride) {
        int j    = idx & 7;
        int lane = (idx >> 3) & 63;
        int ck   = idx >> 9;
        int kc   = ck % KCH;
        int c    = ck / KCH;
        int kl   = ((lane >> 4) << 3) + j;
        float v;
        if (c < 64) {
            int g = c >> 4;
            int m = (c & 15) * 16 + (lane & 15);
            if (kc < 8) v = W_hh[(g*HID + m)*HID + (kc*32 + kl)];
            else        v = W_ih[(g*HID + m)*INDIM + kl];
        } else {
            int o = ((c - 64) << 4) + (lane & 15);
            v = (kc < 8) ? W_out[o*HID + kc*32 + kl] : 0.f;
        }
        Wb[idx] = f2h(v);
    }
    for (int n = tid; n < 1024; n += stride) {
        int c = n >> 4, q = n & 15;
        int g = c >> 4;
        int m = (c & 15) * 16 + q;
        Bc[n] = b_ih[g*HID + m] + b_hh[g*HID + m];
    }
}

__global__ __launch_bounds__(1024) void zero_flags_kernel(int* __restrict__ flags) {
    flags[threadIdx.x] = 0;
}

// 64 blocks x 512 threads (8 waves). Pair = blocks {b, b+8}; hf=(bid>>3)&1,
// tile=(bid&7)|((bid>>4)<<3). Block owns units hf*128..+127; wave wv owns
// unit group ug=hf*8+wv. All B-fragments register-resident.
// Exchange: RELAXED agent atomics (cache-bypass), no acquire/release fences.
__global__ __launch_bounds__(512) void lstm_kernel(
    const float* __restrict__ xin,   // [T][B][32]
    const float* __restrict__ phys,  // [T][B][32]
    const u16*  __restrict__ Wb_,
    const float* __restrict__ Bc,
    const float* __restrict__ b_out,
    u16* __restrict__ xbuf,
    int* __restrict__ flags,
    float* __restrict__ out)         // [2][B][T][32]
{
    const int tid  = threadIdx.x;
    const int lane = tid & 63;
    const int wv   = tid >> 6;
    const int bid  = blockIdx.x;
    const int hf   = (bid >> 3) & 1;
    const int phf  = 1 - hf;
    const int tile = (bid & 7) | ((bid >> 4) << 3);
    const int b0   = tile << 4;

    __shared__ __align__(16) u16   ha[2*2048];        // own h-half, double buffered (8KB)
    __shared__ __align__(16) u16   xring[16][512];    // x fragments, 16 steps (16KB)
    __shared__ __align__(16) float physring[16][512]; // phys, 16 steps (32KB)
    __shared__ __align__(16) float outring[8][256];   // rnn_pred, 8 steps (8KB)

    const f16x8* Wb8 = (const f16x8*)Wb_;

    const int ug = hf*8 + wv;
    const int uw = (ug << 4) + (lane & 15);

    const float bi0 = Bc[((0*16+ug)<<4)+(lane&15)];
    const float bi1 = Bc[((1*16+ug)<<4)+(lane&15)];
    const float bi2 = Bc[((2*16+ug)<<4)+(lane&15)];
    const float bi3 = Bc[((3*16+ug)<<4)+(lane&15)];

    const bool  isP = (wv == 0);
    const int   o_  = (hf << 4) + (lane & 15);
    const float bip = b_out[o_];

    // ---- register-resident B-fragments ----
    f16x8 wOwn[4][5];    // 4 gates x (4 own-h kcs + x kc)
    f16x8 wPar[4][4];    // 4 gates x 4 partner-h kcs
    f16x8 wPrO[4];       // projection, own-h kcs
    f16x8 wPrP[4];       // projection, partner-h kcs
#pragma unroll
    for (int g = 0; g < 4; ++g) {
        const int cg = g*16 + ug;
#pragma unroll
        for (int i = 0; i < 4; ++i)
            wOwn[g][i] = Wb8[(cg*KCH + (4*hf+i))*64 + lane];
        wOwn[g][4] = Wb8[(cg*KCH + 8)*64 + lane];
#pragma unroll
        for (int i = 0; i < 4; ++i)
            wPar[g][i] = Wb8[(cg*KCH + (4*phf+i))*64 + lane];
    }
#pragma unroll
    for (int i = 0; i < 4; ++i) {
        wPrO[i] = Wb8[((64+hf)*KCH + (4*hf+i))*64 + lane];
        wPrP[i] = Wb8[((64+hf)*KCH + (4*phf+i))*64 + lane];
    }

    const int xrow = tid >> 5, xj = tid & 31;
    const int xfs  = (xrow + 16*(xj>>3))*8 + (xj&7);
    const int mr_base = (lane >> 4) << 2;
    const int ul  = uw - hf*128;
    const int hx  = ((ul>>5)<<9) + (16*((ul>>3)&3))*8 + (ul&7);  // + mr*8

    float cst0=0.f,cst1=0.f,cst2=0.f,cst3=0.f;

    // ---- init: zero ha buf0, preload x/phys rings for steps 0..15 ----
    ((uint32_t*)ha)[tid] = 0u;
    ((uint32_t*)ha)[tid + 512] = 0u;
#pragma unroll 4
    for (int s = 0; s < 16; ++s) {
        xring[s][xfs]    = f2h(xin[(size_t)s*BATCH*INDIM + (size_t)b0*INDIM + tid]);
        physring[s][tid] = phys[(size_t)s*BATCH*ODIM + (size_t)b0*ODIM + tid];
    }
    __syncthreads();

    const int* pflag = flags + tile*32 + phf*16;
    int*       mflag = flags + tile*32 + hf*16;

    float* outFull = out;
    float* outRnn  = out + (size_t)BATCH*TSTEPS*ODIM;

    for (int t = 0; t < TSTEPS; ++t) {
        const int bufp = t & 1;
        const int bufn = bufp ^ 1;
        const f16x8* A = (const f16x8*)(ha + bufp*2048);

        // ---- phase 1: x + own-half gate MFMAs; wave0 also proj(own) of h_{t-1} ----
        f32x4 a0={bi0,bi0,bi0,bi0}, a1={bi1,bi1,bi1,bi1};
        f32x4 a2={bi2,bi2,bi2,bi2}, a3={bi3,bi3,bi3,bi3};
        {
            f16x8 afx = ((const f16x8*)xring)[(t&15)*64 + lane];
            a0 = MFMA(afx, wOwn[0][4], a0);
            a1 = MFMA(afx, wOwn[1][4], a1);
            a2 = MFMA(afx, wOwn[2][4], a2);
            a3 = MFMA(afx, wOwn[3][4], a3);
        }
        f16x8 afO0 = A[0*64+lane], afO1 = A[1*64+lane];
        f16x8 afO2 = A[2*64+lane], afO3 = A[3*64+lane];
        a0=MFMA(afO0,wOwn[0][0],a0); a1=MFMA(afO0,wOwn[1][0],a1); a2=MFMA(afO0,wOwn[2][0],a2); a3=MFMA(afO0,wOwn[3][0],a3);
        a0=MFMA(afO1,wOwn[0][1],a0); a1=MFMA(afO1,wOwn[1][1],a1); a2=MFMA(afO1,wOwn[2][1],a2); a3=MFMA(afO1,wOwn[3][1],a3);
        a0=MFMA(afO2,wOwn[0][2],a0); a1=MFMA(afO2,wOwn[1][2],a1); a2=MFMA(afO2,wOwn[2][2],a2); a3=MFMA(afO2,wOwn[3][2],a3);
        a0=MFMA(afO3,wOwn[0][3],a0); a1=MFMA(afO3,wOwn[1][3],a1); a2=MFMA(afO3,wOwn[2][3],a2); a3=MFMA(afO3,wOwn[3][3],a3);

        f32x4 pa = {bip,bip,bip,bip};
        if (isP && t > 0) {
            pa = MFMA(afO0, wPrO[0], pa);
            pa = MFMA(afO1, wPrO[1], pa);
            pa = MFMA(afO2, wPrO[2], pa);
            pa = MFMA(afO3, wPrO[3], pa);
        }

        // ---- phase 3: every wave polls partner flag, then loads partner frags
        //      via relaxed agent atomics (bypass stale L2) ----
        if (t > 0) {
            while (__hip_atomic_load(pflag, __ATOMIC_RELAXED, __HIP_MEMORY_SCOPE_AGENT) < t) {}
            const u64* xb64 = (const u64*)(xbuf + ((size_t)(tile*2 + bufp)*2 + phf)*2048);
            u64 q0 = __hip_atomic_load(xb64 + (0*64+lane)*2,     __ATOMIC_RELAXED, __HIP_MEMORY_SCOPE_AGENT);
            u64 q1 = __hip_atomic_load(xb64 + (0*64+lane)*2 + 1, __ATOMIC_RELAXED, __HIP_MEMORY_SCOPE_AGENT);
            u64 q2 = __hip_atomic_load(xb64 + (1*64+lane)*2,     __ATOMIC_RELAXED, __HIP_MEMORY_SCOPE_AGENT);
            u64 q3 = __hip_atomic_load(xb64 + (1*64+lane)*2 + 1, __ATOMIC_RELAXED, __HIP_MEMORY_SCOPE_AGENT);
            u64 q4 = __hip_atomic_load(xb64 + (2*64+lane)*2,     __ATOMIC_RELAXED, __HIP_MEMORY_SCOPE_AGENT);
            u64 q5 = __hip_atomic_load(xb64 + (2*64+lane)*2 + 1, __ATOMIC_RELAXED, __HIP_MEMORY_SCOPE_AGENT);
            u64 q6 = __hip_atomic_load(xb64 + (3*64+lane)*2,     __ATOMIC_RELAXED, __HIP_MEMORY_SCOPE_AGENT);
            u64 q7 = __hip_atomic_load(xb64 + (3*64+lane)*2 + 1, __ATOMIC_RELAXED, __HIP_MEMORY_SCOPE_AGENT);
            f16x8 afP0 = frag_from_u64(q0,q1);
            f16x8 afP1 = frag_from_u64(q2,q3);
            f16x8 afP2 = frag_from_u64(q4,q5);
            f16x8 afP3 = frag_from_u64(q6,q7);
            a0=MFMA(afP0,wPar[0][0],a0); a1=MFMA(afP0,wPar[1][0],a1); a2=MFMA(afP0,wPar[2][0],a2); a3=MFMA(afP0,wPar[3][0],a3);
            a0=MFMA(afP1,wPar[0][1],a0); a1=MFMA(afP1,wPar[1][1],a1); a2=MFMA(afP1,wPar[2][1],a2); a3=MFMA(afP1,wPar[3][1],a3);
            a0=MFMA(afP2,wPar[0][2],a0); a1=MFMA(afP2,wPar[1][2],a1); a2=MFMA(afP2,wPar[2][2],a2); a3=MFMA(afP2,wPar[3][2],a3);
            a0=MFMA(afP3,wPar[0][3],a0); a1=MFMA(afP3,wPar[1][3],a1); a2=MFMA(afP3,wPar[2][3],a2); a3=MFMA(afP3,wPar[3][3],a3);
            if (isP) {
                pa = MFMA(afP0, wPrP[0], pa);
                pa = MFMA(afP1, wPrP[1], pa);
                pa = MFMA(afP2, wPrP[2], pa);
                pa = MFMA(afP3, wPrP[3], pa);
                const int os = (t-1) & 7;
#pragma unroll
                for (int r = 0; r < 4; ++r)
                    outring[os][(mr_base+r)*16 + (lane&15)] = pa[r];
            }
        }

        // ---- cell update (lane-local); h_t -> LDS own frags ----
#pragma unroll
        for (int r = 0; r < 4; ++r) {
            float gi = sigf(a0[r]);
            float gf = sigf(a1[r]);
            float gg = tanhf_(a2[r]);
            float go = sigf(a3[r]);
            float cs = (r==0)?cst0:(r==1)?cst1:(r==2)?cst2:cst3;
            cs = gf*cs + gi*gg;
            if (r==0) cst0=cs; else if (r==1) cst1=cs; else if (r==2) cst2=cs; else cst3=cs;
            float hv = go*tanhf_(cs);
            ha[bufn*2048 + hx + (mr_base+r)*8] = f2h(hv);
        }

        // ---- publish own h_t: contiguous u64 from LDS (intra-wave data),
        //      one relaxed agent atomic store per thread ----
        asm volatile("" ::: "memory");   // keep ds_write -> ds_read order
        {
            u64 pub = *(const u64*)(ha + bufn*2048 + (size_t)tid*4);
            u64* xdst64 = (u64*)(xbuf + ((size_t)(tile*2 + bufn)*2 + hf)*2048);
            __hip_atomic_store(xdst64 + tid, pub, __ATOMIC_RELAXED, __HIP_MEMORY_SCOPE_AGENT);
        }

        __syncthreads();   // barrier D: drains all waves' vmcnt (stores acked) + LDS
        if (wv == 7 && lane == 0)
            __hip_atomic_store(mflag, t+1, __ATOMIC_RELAXED, __HIP_MEMORY_SCOPE_AGENT);

        // ---- every 8 steps: flush outputs, reload x/phys rings ----
        if ((t & 7) == 0 && t > 0) {
            const int tb = t - 8;
#pragma unroll
            for (int k = 0; k < 4; ++k) {
                int e   = tid + (k << 9);
                int s   = e >> 8;
                int rem = e & 255;
                int row = rem >> 4, oq = rem & 15;
                int sa  = tb + s;
                float rnn = outring[s][row*16 + oq];
                float ph  = physring[sa & 15][row*32 + (hf<<4) + oq];
                size_t ob = (size_t)(b0+row)*TSTEPS*ODIM + (size_t)sa*ODIM + ((hf<<4)+oq);
                outFull[ob] = ph + rnn;
                outRnn [ob] = rnn;
            }
            __syncthreads();   // flush reads done before ring overwrite
            if (t + 8 < TSTEPS) {
#pragma unroll 2
                for (int s = 0; s < 8; ++s) {
                    int ts = t + 8 + s;
                    xring[ts & 15][xfs]    = f2h(xin[(size_t)ts*BATCH*INDIM + (size_t)b0*INDIM + tid]);
                    physring[ts & 15][tid] = phys[(size_t)ts*BATCH*ODIM + (size_t)b0*ODIM + tid];
                }
            }
        }
    }

    // ---- epilogue: rnn(1023) from h_1023 (parity 0), then flush 1016..1023 ----
    if (isP) {
        while (__hip_atomic_load(pflag, __ATOMIC_RELAXED, __HIP_MEMORY_SCOPE_AGENT) < TSTEPS) {}
        const f16x8* A = (const f16x8*)ha;   // h_1023 own half (parity 0)
        f16x8 aO0 = A[0*64+lane], aO1 = A[1*64+lane], aO2 = A[2*64+lane], aO3 = A[3*64+lane];
        const u64* xb64 = (const u64*)(xbuf + ((size_t)(tile*2 + 0)*2 + phf)*2048);
        u64 q0 = __hip_atomic_load(xb64 + (0*64+lane)*2,     __ATOMIC_RELAXED, __HIP_MEMORY_SCOPE_AGENT);
        u64 q1 = __hip_atomic_load(xb64 + (0*64+lane)*2 + 1, __ATOMIC_RELAXED, __HIP_MEMORY_SCOPE_AGENT);
        u64 q2 = __hip_atomic_load(xb64 + (1*64+lane)*2,     __ATOMIC_RELAXED, __HIP_MEMORY_SCOPE_AGENT);
        u64 q3 = __hip_atomic_load(xb64 + (1*64+lane)*2 + 1, __ATOMIC_RELAXED, __HIP_MEMORY_SCOPE_AGENT);
        u64 q4 = __hip_atomic_load(xb64 + (2*64+lane)*2,     __ATOMIC_RELAXED, __HIP_MEMORY_SCOPE_AGENT);
        u64 q5 = __hip_atomic_load(xb64 + (2*64+lane)*2 + 1, __ATOMIC_RELAXED, __HIP_MEMORY_SCOPE_AGENT);
        u64 q6 = __hip_atomic_load(xb64 + (3*64+lane)*2,     __ATOMIC_RELAXED, __HIP_MEMORY_SCOPE_AGENT);
        u64 q7 = __hip_atomic_load(xb64 + (3*64+lane)*2 + 1, __ATOMIC_RELAXED, __HIP_MEMORY_SCOPE_AGENT);
        f16x8 aP0 = frag_from_u64(q0,q1);
        f16x8 aP1 = frag_from_u64(q2,q3);
        f16x8 aP2 = frag_from_u64(q4,q5);
        f16x8 aP3 = frag_from_u64(q6,q7);
        f32x4 pa = {bip,bip,bip,bip};
        pa = MFMA(aO0, wPrO[0], pa); pa = MFMA(aO1, wPrO[1], pa);
        pa = MFMA(aO2, wPrO[2], pa); pa = MFMA(aO3, wPrO[3], pa);
        pa = MFMA(aP0, wPrP[0], pa); pa = MFMA(aP1, wPrP[1], pa);
        pa = MFMA(aP2, wPrP[2], pa); pa = MFMA(aP3, wPrP[3], pa);
#pragma unroll
        for (int r = 0; r < 4; ++r)
            outring[7][(mr_base+r)*16 + (lane&15)] = pa[r];
    }
    __syncthreads();
#pragma unroll
    for (int k = 0; k < 4; ++k) {
        int e   = tid + (k << 9);
        int s   = e >> 8;
        int rem = e & 255;
        int row = rem >> 4, oq = rem & 15;
        int sa  = 1016 + s;
        float rnn = outring[s][row*16 + oq];
        float ph  = physring[sa & 15][row*32 + (hf<<4) + oq];
        size_t ob = (size_t)(b0+row)*TSTEPS*ODIM + (size_t)sa*ODIM + ((hf<<4)+oq);
        outFull[ob] = ph + rnn;
        outRnn [ob] = rnn;
    }
}

extern "C" void kernel_launch(void* const* d_in, const int* in_sizes, int n_in,
                              void* d_out, int out_size, void* d_ws, size_t ws_size,
                              hipStream_t stream) {
    const float* xin   = (const float*)d_in[0];
    const float* phys  = (const float*)d_in[1];
    const float* W_ih  = (const float*)d_in[2];
    const float* W_hh  = (const float*)d_in[3];
    const float* b_ih  = (const float*)d_in[4];
    const float* b_hh  = (const float*)d_in[5];
    const float* W_out = (const float*)d_in[6];
    const float* b_out = (const float*)d_in[7];

    char*  ws    = (char*)d_ws;
    u16*   Wb    = (u16*)ws;
    float* Bc    = (float*)(ws + WS_BC);
    u16*   xbuf  = (u16*)(ws + WS_XBUF);
    int*   flags = (int*)(ws + WS_FLAG);

    prepack_kernel<<<256, 256, 0, stream>>>(W_ih, W_hh, b_ih, b_hh, W_out, Wb, Bc);
    zero_flags_kernel<<<1, 1024, 0, stream>>>(flags);
    lstm_kernel<<<64, 512, 0, stream>>>(xin, phys, Wb, Bc, b_out, xbuf, flags, (float*)d_out);
}

// Round 10
// 2728.684 us; speedup vs baseline: 9.0823x; 1.0498x over previous
//
#include <hip/hip_runtime.h>
#include <hip/hip_bf16.h>
#include <stdint.h>

typedef unsigned short u16;
typedef unsigned long long u64;
typedef __attribute__((ext_vector_type(8))) _Float16 f16x8;
typedef __attribute__((ext_vector_type(4))) float f32x4;

#define TSTEPS 1024
#define BATCH  512
#define INDIM  32
#define HID    256
#define ODIM   32
#define NCH    66
#define KCH    9

// ---------------- workspace layout (bytes) ----------------
// Wb   u16[66*9*64*8]        @ 0       (608256)
// Bc   float[1024]           @ 608256  (4096)
// xbuf u64[32][2][8][128]    @ 612352  (524288)  h exchange, tag-in-data
#define WS_BC   (NCH*KCH*64*8*2)
#define WS_XBUF (WS_BC + 4096)

#define MFMA(a,b,c) __builtin_amdgcn_mfma_f32_16x16x32_f16((a),(b),(c),0,0,0)
#define AGL(p)   __hip_atomic_load((p),      __ATOMIC_RELAXED, __HIP_MEMORY_SCOPE_AGENT)
#define AGS(p,v) __hip_atomic_store((p),(v), __ATOMIC_RELAXED, __HIP_MEMORY_SCOPE_AGENT)

__device__ __forceinline__ u16 f2h(float v){ _Float16 h=(_Float16)v; return *(u16*)&h; }
__device__ __forceinline__ float sigf(float x){ return 1.0f/(1.0f+__expf(-x)); }
__device__ __forceinline__ float tanhf_(float x){
    float ax=fabsf(x); float e=__expf(-2.f*ax); float t=(1.f-e)/(1.f+e); return copysignf(t,x);
}
__device__ __forceinline__ f16x8 frag_from_u64(u64 lo, u64 hi){
    union { u64 q[2]; f16x8 v; } u; u.q[0]=lo; u.q[1]=hi; return u.v;
}
__device__ __forceinline__ f16x8 cvt8(float4 a, float4 b){
    f16x8 r;
    r[0]=(_Float16)a.x; r[1]=(_Float16)a.y; r[2]=(_Float16)a.z; r[3]=(_Float16)a.w;
    r[4]=(_Float16)b.x; r[5]=(_Float16)b.y; r[6]=(_Float16)b.z; r[7]=(_Float16)b.w;
    return r;
}

// Pack weights into MFMA B-fragment order (fp16) — unchanged from R8 (proven).
__global__ __launch_bounds__(256) void prepack_kernel(
    const float* __restrict__ W_ih, const float* __restrict__ W_hh,
    const float* __restrict__ b_ih, const float* __restrict__ b_hh,
    const float* __restrict__ W_out,
    u16* __restrict__ Wb, float* __restrict__ Bc)
{
    int tid = blockIdx.x*blockDim.x + threadIdx.x;
    int stride = gridDim.x*blockDim.x;
    const int TOT = NCH*KCH*64*8;
    for (int idx = tid; idx < TOT; idx += stride) {
        int j    = idx & 7;
        int lane = (idx >> 3) & 63;
        int ck   = idx >> 9;
        int kc   = ck % KCH;
        int c    = ck / KCH;
        int kl   = ((lane >> 4) << 3) + j;
        float v;
        if (c < 64) {
            int g = c >> 4;
            int m = (c & 15) * 16 + (lane & 15);
            if (kc < 8) v = W_hh[(g*HID + m)*HID + (kc*32 + kl)];
            else        v = W_ih[(g*HID + m)*INDIM + kl];
        } else {
            int o = ((c - 64) << 4) + (lane & 15);
            v = (kc < 8) ? W_out[o*HID + kc*32 + kl] : 0.f;
        }
        Wb[idx] = f2h(v);
    }
    for (int n = tid; n < 1024; n += stride) {
        int c = n >> 4, qq = n & 15;
        int g = c >> 4;
        int m = (c & 15) * 16 + qq;
        Bc[n] = b_ih[g*HID + m] + b_hh[g*HID + m];
    }
}

// Fill exchange buffer with tag=1 sentinels via DEVICE-SCOPE stores so the
// first polls (expecting tag 0) always wait. Runs every launch (replay-safe).
__global__ __launch_bounds__(256) void init_xbuf_kernel(u64* __restrict__ xb) {
    int i = blockIdx.x*256 + threadIdx.x;   // 256 blocks x 256 = 65536 u64
    AGS(xb + i, 1ull);
}

// 512 blocks x 64 threads: one wave per block. block = (tile 0..31, ug 0..15).
// Wave owns units ug*16..+15 (all 4 gates) of its tile's 16 batch rows.
// ALL h traffic goes through L3 via device-scope u64 stores/loads with a
// 1-bit generation tag embedded in bit 0 of each u64. No barriers, no flags.
// Waves ug==0 / ug==8 additionally compute the W_out projection (o 0-15/16-31).
__global__ __launch_bounds__(64, 1) void lstm_kernel(
    const float* __restrict__ xin,   // [T][B][32]
    const float* __restrict__ phys,  // [T][B][32]
    const u16*  __restrict__ Wb_,
    const float* __restrict__ Bc,
    const float* __restrict__ b_out,
    u64* __restrict__ xb,            // exchange: [tile][parity][kc][128 u64]
    float* __restrict__ out)         // [2][B][T][32]
{
    const int lane = threadIdx.x;
    const int bid  = blockIdx.x;
    const int tile = bid >> 4;
    const int ug   = bid & 15;
    const int b0   = tile << 4;
    const int q    = lane & 15;
    const int rg   = lane >> 4;
    const int mrb  = rg << 2;

    __shared__ u16 scr[256];   // wave-private transpose scratch (512B)

    const f16x8* Wb8 = (const f16x8*)Wb_;

    // ---- register-resident weights: 4 gates x 9 kc + 8 proj kc ----
    f16x8 wg0[KCH], wg1[KCH], wg2[KCH], wg3[KCH];
#pragma unroll
    for (int kc = 0; kc < KCH; ++kc) {
        wg0[kc] = Wb8[((0*16+ug)*KCH + kc)*64 + lane];
        wg1[kc] = Wb8[((1*16+ug)*KCH + kc)*64 + lane];
        wg2[kc] = Wb8[((2*16+ug)*KCH + kc)*64 + lane];
        wg3[kc] = Wb8[((3*16+ug)*KCH + kc)*64 + lane];
    }
    f16x8 wp[8];
#pragma unroll
    for (int kc = 0; kc < 8; ++kc)
        wp[kc] = Wb8[((64 + (ug>>3))*KCH + kc)*64 + lane];

    const float bi0 = Bc[((0*16+ug)<<4)+q];
    const float bi1 = Bc[((1*16+ug)<<4)+q];
    const float bi2 = Bc[((2*16+ug)<<4)+q];
    const float bi3 = Bc[((3*16+ug)<<4)+q];

    const bool  isP = (ug == 0) || (ug == 8);
    const int   o_  = ((ug >> 3) << 4) + q;
    const float bip = isP ? b_out[o_] : 0.f;

    // phys state (proj waves only): holds phys[t-1] when outputs t-1 are written
    float ph0=0.f, ph1=0.f, ph2=0.f, ph3=0.f;
    if (isP) {
        ph0 = phys[(size_t)(b0+mrb+0)*ODIM + o_];
        ph1 = phys[(size_t)(b0+mrb+1)*ODIM + o_];
        ph2 = phys[(size_t)(b0+mrb+2)*ODIM + o_];
        ph3 = phys[(size_t)(b0+mrb+3)*ODIM + o_];
    }

    // x prefetch (2-deep): lane loads x[t][b0+q][8*rg .. +7]
    const float* xbase = xin + (size_t)(b0 + q)*INDIM + (rg << 3);
    float4 xc0 = *(const float4*)(xbase);
    float4 xc1 = *(const float4*)(xbase + 4);
    float4 xn0 = *(const float4*)(xbase + (size_t)BATCH*INDIM);
    float4 xn1 = *(const float4*)(xbase + (size_t)BATCH*INDIM + 4);

    // publish constants: lane's u64 slot inside its kc fragment
    const int m_ = (lane>>1) & 15, s_ = lane>>5, c_ = lane & 1;
    const int gw = ((m_ + 16*(((ug&1)<<1) + s_)) << 1) + c_;   // 0..127
    const int kcSelf = ug >> 1;
    u64* xbT = xb + (size_t)tile*2048;   // [parity][kc][128]

    float* outFull = out;
    float* outRnn  = out + (size_t)BATCH*TSTEPS*ODIM;

    float cs0=0.f, cs1=0.f, cs2=0.f, cs3=0.f;
    f16x8 h0,h1,h2,h3,h4,h5,h6,h7;

    for (int t = 0; t < TSTEPS; ++t) {
        // ---- poll h_{t-1}: tag-validated device-scope loads (no flags) ----
        if (t > 0) {
            const u64* src = xbT + (size_t)(t&1)*1024 + lane*2;
            const u64 gexp = (u64)(((t-1) >> 1) & 1);
            u64 v0,v1,v2,v3,v4,v5,v6,v7,v8,v9,v10,v11,v12,v13,v14,v15;
            for (;;) {
                v0 =AGL(src+0*128); v1 =AGL(src+0*128+1);
                v2 =AGL(src+1*128); v3 =AGL(src+1*128+1);
                v4 =AGL(src+2*128); v5 =AGL(src+2*128+1);
                v6 =AGL(src+3*128); v7 =AGL(src+3*128+1);
                v8 =AGL(src+4*128); v9 =AGL(src+4*128+1);
                v10=AGL(src+5*128); v11=AGL(src+5*128+1);
                v12=AGL(src+6*128); v13=AGL(src+6*128+1);
                v14=AGL(src+7*128); v15=AGL(src+7*128+1);
                u64 bad = ((v0^gexp)|(v1^gexp)|(v2^gexp)|(v3^gexp)
                          |(v4^gexp)|(v5^gexp)|(v6^gexp)|(v7^gexp)
                          |(v8^gexp)|(v9^gexp)|(v10^gexp)|(v11^gexp)
                          |(v12^gexp)|(v13^gexp)|(v14^gexp)|(v15^gexp)) & 1ull;
                if (!__any((int)bad)) break;
            }
            h0=frag_from_u64(v0,v1);   h1=frag_from_u64(v2,v3);
            h2=frag_from_u64(v4,v5);   h3=frag_from_u64(v6,v7);
            h4=frag_from_u64(v8,v9);   h5=frag_from_u64(v10,v11);
            h6=frag_from_u64(v12,v13); h7=frag_from_u64(v14,v15);
        }

        // ---- gates ----
        f32x4 a0={bi0,bi0,bi0,bi0}, a1={bi1,bi1,bi1,bi1};
        f32x4 a2={bi2,bi2,bi2,bi2}, a3={bi3,bi3,bi3,bi3};
        {
            f16x8 ax = cvt8(xc0, xc1);
            a0=MFMA(ax,wg0[8],a0); a1=MFMA(ax,wg1[8],a1);
            a2=MFMA(ax,wg2[8],a2); a3=MFMA(ax,wg3[8],a3);
        }
        if (t > 0) {
            a0=MFMA(h0,wg0[0],a0); a1=MFMA(h0,wg1[0],a1); a2=MFMA(h0,wg2[0],a2); a3=MFMA(h0,wg3[0],a3);
            a0=MFMA(h1,wg0[1],a0); a1=MFMA(h1,wg1[1],a1); a2=MFMA(h1,wg2[1],a2); a3=MFMA(h1,wg3[1],a3);
            a0=MFMA(h2,wg0[2],a0); a1=MFMA(h2,wg1[2],a1); a2=MFMA(h2,wg2[2],a2); a3=MFMA(h2,wg3[2],a3);
            a0=MFMA(h3,wg0[3],a0); a1=MFMA(h3,wg1[3],a1); a2=MFMA(h3,wg2[3],a2); a3=MFMA(h3,wg3[3],a3);
            a0=MFMA(h4,wg0[4],a0); a1=MFMA(h4,wg1[4],a1); a2=MFMA(h4,wg2[4],a2); a3=MFMA(h4,wg3[4],a3);
            a0=MFMA(h5,wg0[5],a0); a1=MFMA(h5,wg1[5],a1); a2=MFMA(h5,wg2[5],a2); a3=MFMA(h5,wg3[5],a3);
            a0=MFMA(h6,wg0[6],a0); a1=MFMA(h6,wg1[6],a1); a2=MFMA(h6,wg2[6],a2); a3=MFMA(h6,wg3[6],a3);
            a0=MFMA(h7,wg0[7],a0); a1=MFMA(h7,wg1[7],a1); a2=MFMA(h7,wg2[7],a2); a3=MFMA(h7,wg3[7],a3);
        }

        // ---- shift x prefetch (load t+2) ----
        {
            int tt = (t+2 < TSTEPS) ? (t+2) : (TSTEPS-1);
            const float* p = xbase + (size_t)tt*BATCH*INDIM;
            float4 nn0 = *(const float4*)p;
            float4 nn1 = *(const float4*)(p + 4);
            xc0 = xn0; xc1 = xn1; xn0 = nn0; xn1 = nn1;
        }

        // ---- projection of h_{t-1} -> outputs t-1 (proj waves) ----
        if (isP && t > 0) {
            f32x4 pa = {bip,bip,bip,bip};
            pa=MFMA(h0,wp[0],pa); pa=MFMA(h1,wp[1],pa);
            pa=MFMA(h2,wp[2],pa); pa=MFMA(h3,wp[3],pa);
            pa=MFMA(h4,wp[4],pa); pa=MFMA(h5,wp[5],pa);
            pa=MFMA(h6,wp[6],pa); pa=MFMA(h7,wp[7],pa);
            const size_t ob = (size_t)(b0+mrb)*TSTEPS*ODIM + (size_t)(t-1)*ODIM + o_;
            const size_t rs = (size_t)TSTEPS*ODIM;
            outFull[ob+0*rs] = ph0 + pa[0];  outRnn[ob+0*rs] = pa[0];
            outFull[ob+1*rs] = ph1 + pa[1];  outRnn[ob+1*rs] = pa[1];
            outFull[ob+2*rs] = ph2 + pa[2];  outRnn[ob+2*rs] = pa[2];
            outFull[ob+3*rs] = ph3 + pa[3];  outRnn[ob+3*rs] = pa[3];
            const float* pb = phys + (size_t)t*BATCH*ODIM + (size_t)(b0+mrb)*ODIM + o_;
            ph0 = pb[0*ODIM]; ph1 = pb[1*ODIM]; ph2 = pb[2*ODIM]; ph3 = pb[3*ODIM];
        }

        // ---- cell update (lane-local) -> scratch transpose -> tagged publish ----
        {
            float gi,gf,gg,go,hv;
            gi=sigf(a0[0]); gf=sigf(a1[0]); gg=tanhf_(a2[0]); go=sigf(a3[0]);
            cs0 = gf*cs0 + gi*gg; hv = go*tanhf_(cs0);
            scr[(mrb+0 + 16*(q>>3))*8 + (q&7)] = f2h(hv);
            gi=sigf(a0[1]); gf=sigf(a1[1]); gg=tanhf_(a2[1]); go=sigf(a3[1]);
            cs1 = gf*cs1 + gi*gg; hv = go*tanhf_(cs1);
            scr[(mrb+1 + 16*(q>>3))*8 + (q&7)] = f2h(hv);
            gi=sigf(a0[2]); gf=sigf(a1[2]); gg=tanhf_(a2[2]); go=sigf(a3[2]);
            cs2 = gf*cs2 + gi*gg; hv = go*tanhf_(cs2);
            scr[(mrb+2 + 16*(q>>3))*8 + (q&7)] = f2h(hv);
            gi=sigf(a0[3]); gf=sigf(a1[3]); gg=tanhf_(a2[3]); go=sigf(a3[3]);
            cs3 = gf*cs3 + gi*gg; hv = go*tanhf_(cs3);
            scr[(mrb+3 + 16*(q>>3))*8 + (q&7)] = f2h(hv);

            // wave-private LDS read-back (same-wave DS ops are ordered)
            u16 w0b=scr[lane*4+0], w1b=scr[lane*4+1], w2b=scr[lane*4+2], w3b=scr[lane*4+3];
            u64 pub = (u64)w0b | ((u64)w1b<<16) | ((u64)w2b<<32) | ((u64)w3b<<48);
            pub = (pub & ~1ull) | (u64)((t>>1)&1);   // generation tag
            AGS(xbT + (size_t)((t+1)&1)*1024 + kcSelf*128 + gw, pub);
        }
    }

    // ---- epilogue (proj waves): poll h_1023 (parity 0, g=1) -> outputs 1023 ----
    if (isP) {
        const u64* src = xbT + lane*2;
        u64 v0,v1,v2,v3,v4,v5,v6,v7,v8,v9,v10,v11,v12,v13,v14,v15;
        for (;;) {
            v0 =AGL(src+0*128); v1 =AGL(src+0*128+1);
            v2 =AGL(src+1*128); v3 =AGL(src+1*128+1);
            v4 =AGL(src+2*128); v5 =AGL(src+2*128+1);
            v6 =AGL(src+3*128); v7 =AGL(src+3*128+1);
            v8 =AGL(src+4*128); v9 =AGL(src+4*128+1);
            v10=AGL(src+5*128); v11=AGL(src+5*128+1);
            v12=AGL(src+6*128); v13=AGL(src+6*128+1);
            v14=AGL(src+7*128); v15=AGL(src+7*128+1);
            u64 bad = ((v0^1ull)|(v1^1ull)|(v2^1ull)|(v3^1ull)
                      |(v4^1ull)|(v5^1ull)|(v6^1ull)|(v7^1ull)
                      |(v8^1ull)|(v9^1ull)|(v10^1ull)|(v11^1ull)
                      |(v12^1ull)|(v13^1ull)|(v14^1ull)|(v15^1ull)) & 1ull;
            if (!__any((int)bad)) break;
        }
        h0=frag_from_u64(v0,v1);   h1=frag_from_u64(v2,v3);
        h2=frag_from_u64(v4,v5);   h3=frag_from_u64(v6,v7);
        h4=frag_from_u64(v8,v9);   h5=frag_from_u64(v10,v11);
        h6=frag_from_u64(v12,v13); h7=frag_from_u64(v14,v15);

        f32x4 pa = {bip,bip,bip,bip};
        pa=MFMA(h0,wp[0],pa); pa=MFMA(h1,wp[1],pa);
        pa=MFMA(h2,wp[2],pa); pa=MFMA(h3,wp[3],pa);
        pa=MFMA(h4,wp[4],pa); pa=MFMA(h5,wp[5],pa);
        pa=MFMA(h6,wp[6],pa); pa=MFMA(h7,wp[7],pa);
        const size_t ob = (size_t)(b0+mrb)*TSTEPS*ODIM + (size_t)1023*ODIM + o_;
        const size_t rs = (size_t)TSTEPS*ODIM;
        outFull[ob+0*rs] = ph0 + pa[0];  outRnn[ob+0*rs] = pa[0];
        outFull[ob+1*rs] = ph1 + pa[1];  outRnn[ob+1*rs] = pa[1];
        outFull[ob+2*rs] = ph2 + pa[2];  outRnn[ob+2*rs] = pa[2];
        outFull[ob+3*rs] = ph3 + pa[3];  outRnn[ob+3*rs] = pa[3];
    }
}

extern "C" void kernel_launch(void* const* d_in, const int* in_sizes, int n_in,
                              void* d_out, int out_size, void* d_ws, size_t ws_size,
                              hipStream_t stream) {
    const float* xin   = (const float*)d_in[0];
    const float* phys  = (const float*)d_in[1];
    const float* W_ih  = (const float*)d_in[2];
    const float* W_hh  = (const float*)d_in[3];
    const float* b_ih  = (const float*)d_in[4];
    const float* b_hh  = (const float*)d_in[5];
    const float* W_out = (const float*)d_in[6];
    const float* b_out = (const float*)d_in[7];

    char*  ws = (char*)d_ws;
    u16*   Wb = (u16*)ws;
    float* Bc = (float*)(ws + WS_BC);
    u64*   xb = (u64*)(ws + WS_XBUF);

    prepack_kernel<<<256, 256, 0, stream>>>(W_ih, W_hh, b_ih, b_hh, W_out, Wb, Bc);
    init_xbuf_kernel<<<256, 256, 0, stream>>>(xb);
    lstm_kernel<<<512, 64, 0, stream>>>(xin, phys, Wb, Bc, b_out, xb, (float*)d_out);
}

// Round 11
// 2213.622 us; speedup vs baseline: 11.1955x; 1.2327x over previous
//
#include <hip/hip_runtime.h>
#include <hip/hip_bf16.h>
#include <stdint.h>

typedef unsigned short u16;
typedef unsigned char  u8;
typedef unsigned int   u32;
typedef unsigned long long u64;
typedef __attribute__((ext_vector_type(8))) _Float16 f16x8;
typedef __attribute__((ext_vector_type(4))) float f32x4;

#define TSTEPS 1024
#define BATCH  512
#define INDIM  32
#define HID    256
#define ODIM   32
#define NCH    66
#define KCH    9

// ---------------- workspace layout (bytes) ----------------
// Wb @ 0 (608256); Bc @ 608256 (4096)
// xp u64[32][2][8][128] @ 612352  (524288)  sc0/L2 exchange (tag-in-data)
// xs u64[32][2][8][128] @ 1136640 (524288)  device-scope shadow (always written)
#define WS_BC (NCH*KCH*64*8*2)
#define WS_XP (WS_BC + 4096)
#define WS_XS (WS_XP + 32*2*8*128*8)

#define MFMA(a,b,c) __builtin_amdgcn_mfma_f32_16x16x32_f16((a),(b),(c),0,0,0)
#define AGL(p)   __hip_atomic_load((p),      __ATOMIC_RELAXED, __HIP_MEMORY_SCOPE_AGENT)
#define AGS(p,v) __hip_atomic_store((p),(v), __ATOMIC_RELAXED, __HIP_MEMORY_SCOPE_AGENT)

__device__ __forceinline__ u16 f2h(float v){ _Float16 h=(_Float16)v; return *(u16*)&h; }
__device__ __forceinline__ float sigf(float x){ return 1.0f/(1.0f+__expf(-x)); }
__device__ __forceinline__ float tanhf_(float x){
    float ax=fabsf(x); float e=__expf(-2.f*ax); float t=(1.f-e)/(1.f+e); return copysignf(t,x);
}
__device__ __forceinline__ f16x8 cvt8(float4 a, float4 b){
    f16x8 r;
    r[0]=(_Float16)a.x; r[1]=(_Float16)a.y; r[2]=(_Float16)a.z; r[3]=(_Float16)a.w;
    r[4]=(_Float16)b.x; r[5]=(_Float16)b.y; r[6]=(_Float16)b.z; r[7]=(_Float16)b.w;
    return r;
}

// 4x dwordx4 sc0 loads (bypass L1, served by the shared per-XCD L2)
__device__ __forceinline__ void ld4_sc0(const u8* p, uint4& a, uint4& b, uint4& c, uint4& d){
    asm volatile(
        "global_load_dwordx4 %0, %4, off sc0\n\t"
        "global_load_dwordx4 %1, %4, off offset:1024 sc0\n\t"
        "global_load_dwordx4 %2, %4, off offset:2048 sc0\n\t"
        "global_load_dwordx4 %3, %4, off offset:3072 sc0\n\t"
        "s_waitcnt vmcnt(0)"
        : "=&v"(a), "=&v"(b), "=&v"(c), "=&v"(d)
        : "v"(p) : "memory");
    __builtin_amdgcn_sched_barrier(0);
}
__device__ __forceinline__ void st_u64_sc0(u64* p, u64 v){
    asm volatile("global_store_dwordx2 %0, %1, off sc0" :: "v"(p), "v"(v) : "memory");
}

// Pack weights into MFMA B-fragment order (fp16) — unchanged (proven R8/R10).
__global__ __launch_bounds__(256) void prepack_kernel(
    const float* __restrict__ W_ih, const float* __restrict__ W_hh,
    const float* __restrict__ b_ih, const float* __restrict__ b_hh,
    const float* __restrict__ W_out,
    u16* __restrict__ Wb, float* __restrict__ Bc)
{
    int tid = blockIdx.x*blockDim.x + threadIdx.x;
    int stride = gridDim.x*blockDim.x;
    const int TOT = NCH*KCH*64*8;
    for (int idx = tid; idx < TOT; idx += stride) {
        int j    = idx & 7;
        int lane = (idx >> 3) & 63;
        int ck   = idx >> 9;
        int kc   = ck % KCH;
        int c    = ck / KCH;
        int kl   = ((lane >> 4) << 3) + j;
        float v;
        if (c < 64) {
            int g = c >> 4;
            int m = (c & 15) * 16 + (lane & 15);
            if (kc < 8) v = W_hh[(g*HID + m)*HID + (kc*32 + kl)];
            else        v = W_ih[(g*HID + m)*INDIM + kl];
        } else {
            int o = ((c - 64) << 4) + (lane & 15);
            v = (kc < 8) ? W_out[o*HID + kc*32 + kl] : 0.f;
        }
        Wb[idx] = f2h(v);
    }
    for (int n = tid; n < 1024; n += stride) {
        int c = n >> 4, qq = n & 15;
        int g = c >> 4;
        int m = (c & 15) * 16 + qq;
        Bc[n] = b_ih[g*HID + m] + b_hh[g*HID + m];
    }
}

// Sentinel tag=1 in BOTH buffers every launch (replay-safe; kernel boundary
// flush makes these visible to both sc0 and AGL readers).
__global__ __launch_bounds__(256) void init_xbuf_kernel(u64* __restrict__ xp, u64* __restrict__ xs) {
    int i = blockIdx.x*256 + threadIdx.x;   // 256 blocks x 256 = 65536 u64 each
    AGS(xp + i, 1ull);
    AGS(xs + i, 1ull);
}

// 512 blocks x 64 threads; tile = bid&31, ug = bid>>5 (round-robin => all 16
// waves of a tile on ONE XCD => sc0 polls are L2-served). Wave owns units
// ug*16..+15 (all 4 gates, lane-local cell). Publish: tagged u64s via sc0 AND
// device-scope shadow. Poll: sc0 optimistic, sticky demote to shadow after
// 256 stale iters (wave-uniform) => deadlock-free for any XCD placement.
__global__ __launch_bounds__(64, 1) void lstm_kernel(
    const float* __restrict__ xin,   // [T][B][32]
    const float* __restrict__ phys,  // [T][B][32]
    const u16*  __restrict__ Wb_,
    const float* __restrict__ Bc,
    const float* __restrict__ b_out,
    u64* __restrict__ xp,            // L2 exchange
    u64* __restrict__ xs,            // L3 shadow
    float* __restrict__ out)         // [2][B][T][32]
{
    const int lane = threadIdx.x;
    const int bid  = blockIdx.x;
    const int tile = bid & 31;
    const int ug   = bid >> 5;
    const int b0   = tile << 4;
    const int q    = lane & 15;
    const int rg   = lane >> 4;
    const int mrb  = rg << 2;

    __shared__ u16 scr[256];   // wave-private transpose scratch

    const f16x8* Wb8 = (const f16x8*)Wb_;

    // ---- register-resident weights ----
    f16x8 wg0[KCH], wg1[KCH], wg2[KCH], wg3[KCH];
#pragma unroll
    for (int kc = 0; kc < KCH; ++kc) {
        wg0[kc] = Wb8[((0*16+ug)*KCH + kc)*64 + lane];
        wg1[kc] = Wb8[((1*16+ug)*KCH + kc)*64 + lane];
        wg2[kc] = Wb8[((2*16+ug)*KCH + kc)*64 + lane];
        wg3[kc] = Wb8[((3*16+ug)*KCH + kc)*64 + lane];
    }
    f16x8 wp[8];
#pragma unroll
    for (int kc = 0; kc < 8; ++kc)
        wp[kc] = Wb8[((64 + (ug>>3))*KCH + kc)*64 + lane];

    const float bi0 = Bc[((0*16+ug)<<4)+q];
    const float bi1 = Bc[((1*16+ug)<<4)+q];
    const float bi2 = Bc[((2*16+ug)<<4)+q];
    const float bi3 = Bc[((3*16+ug)<<4)+q];

    const bool  isP = (ug == 0) || (ug == 8);
    const int   o_  = ((ug >> 3) << 4) + q;
    const float bip = isP ? b_out[o_] : 0.f;

    float ph0=0.f, ph1=0.f, ph2=0.f, ph3=0.f;
    if (isP) {
        ph0 = phys[(size_t)(b0+mrb+0)*ODIM + o_];
        ph1 = phys[(size_t)(b0+mrb+1)*ODIM + o_];
        ph2 = phys[(size_t)(b0+mrb+2)*ODIM + o_];
        ph3 = phys[(size_t)(b0+mrb+3)*ODIM + o_];
    }

    // x prefetch (2-deep)
    const float* xbase = xin + (size_t)(b0 + q)*INDIM + (rg << 3);
    float4 xc0 = *(const float4*)(xbase);
    float4 xc1 = *(const float4*)(xbase + 4);
    float4 xn0 = *(const float4*)(xbase + (size_t)BATCH*INDIM);
    float4 xn1 = *(const float4*)(xbase + (size_t)BATCH*INDIM + 4);

    // publish constants
    const int m_ = (lane>>1) & 15, s_ = lane>>5, c_ = lane & 1;
    const int gw = ((m_ + 16*(((ug&1)<<1) + s_)) << 1) + c_;   // 0..127
    const int kcSelf = ug >> 1;
    u64* xpT = xp + (size_t)tile*2048;
    u64* xsT = xs + (size_t)tile*2048;

    float* outFull = out;
    float* outRnn  = out + (size_t)BATCH*TSTEPS*ODIM;

    float cs0=0.f, cs1=0.f, cs2=0.f, cs3=0.f;
    f16x8 h0,h1,h2,h3,h4,h5,h6,h7;
    bool fastm = true;

    for (int t = 0; t < TSTEPS; ++t) {
        // ---- x-part gates first (no h dependency, overlaps the poll) ----
        f32x4 a0={bi0,bi0,bi0,bi0}, a1={bi1,bi1,bi1,bi1};
        f32x4 a2={bi2,bi2,bi2,bi2}, a3={bi3,bi3,bi3,bi3};
        {
            f16x8 ax = cvt8(xc0, xc1);
            a0=MFMA(ax,wg0[8],a0); a1=MFMA(ax,wg1[8],a1);
            a2=MFMA(ax,wg2[8],a2); a3=MFMA(ax,wg3[8],a3);
        }

        // ---- poll h_{t-1}: tag-validated; sc0/L2 fast, shadow/L3 fallback ----
        if (t > 0) {
            const u8*  pb = (const u8*)xpT + (size_t)(t&1)*8192 + lane*16;
            const u64* sb = xsT + (size_t)(t&1)*1024 + lane*2;
            const u32  gx = (u32)(((t-1) >> 1) & 1);
            union U { uint4 u; f16x8 h; u64 qq[2]; } A,B,C,D,E,F,G,H;
            int iter = 0;
            for (;;) {
                if (fastm) {
                    ld4_sc0(pb,        A.u,B.u,C.u,D.u);   // kc 0..3
                    ld4_sc0(pb + 4096, E.u,F.u,G.u,H.u);   // kc 4..7
                } else {
                    A.qq[0]=AGL(sb+0*128); A.qq[1]=AGL(sb+0*128+1);
                    B.qq[0]=AGL(sb+1*128); B.qq[1]=AGL(sb+1*128+1);
                    C.qq[0]=AGL(sb+2*128); C.qq[1]=AGL(sb+2*128+1);
                    D.qq[0]=AGL(sb+3*128); D.qq[1]=AGL(sb+3*128+1);
                    E.qq[0]=AGL(sb+4*128); E.qq[1]=AGL(sb+4*128+1);
                    F.qq[0]=AGL(sb+5*128); F.qq[1]=AGL(sb+5*128+1);
                    G.qq[0]=AGL(sb+6*128); G.qq[1]=AGL(sb+6*128+1);
                    H.qq[0]=AGL(sb+7*128); H.qq[1]=AGL(sb+7*128+1);
                }
                u32 bad = ((A.u.x^gx)|(A.u.z^gx)|(B.u.x^gx)|(B.u.z^gx)
                          |(C.u.x^gx)|(C.u.z^gx)|(D.u.x^gx)|(D.u.z^gx)
                          |(E.u.x^gx)|(E.u.z^gx)|(F.u.x^gx)|(F.u.z^gx)
                          |(G.u.x^gx)|(G.u.z^gx)|(H.u.x^gx)|(H.u.z^gx)) & 1u;
                if (!__any((int)bad)) { h0=A.h;h1=B.h;h2=C.h;h3=D.h;h4=E.h;h5=F.h;h6=G.h;h7=H.h; break; }
                if (fastm && ++iter >= 256) fastm = false;   // sticky, wave-uniform
            }

            // ---- h-part gates ----
            a0=MFMA(h0,wg0[0],a0); a1=MFMA(h0,wg1[0],a1); a2=MFMA(h0,wg2[0],a2); a3=MFMA(h0,wg3[0],a3);
            a0=MFMA(h1,wg0[1],a0); a1=MFMA(h1,wg1[1],a1); a2=MFMA(h1,wg2[1],a2); a3=MFMA(h1,wg3[1],a3);
            a0=MFMA(h2,wg0[2],a0); a1=MFMA(h2,wg1[2],a1); a2=MFMA(h2,wg2[2],a2); a3=MFMA(h2,wg3[2],a3);
            a0=MFMA(h3,wg0[3],a0); a1=MFMA(h3,wg1[3],a1); a2=MFMA(h3,wg2[3],a2); a3=MFMA(h3,wg3[3],a3);
            a0=MFMA(h4,wg0[4],a0); a1=MFMA(h4,wg1[4],a1); a2=MFMA(h4,wg2[4],a2); a3=MFMA(h4,wg3[4],a3);
            a0=MFMA(h5,wg0[5],a0); a1=MFMA(h5,wg1[5],a1); a2=MFMA(h5,wg2[5],a2); a3=MFMA(h5,wg3[5],a3);
            a0=MFMA(h6,wg0[6],a0); a1=MFMA(h6,wg1[6],a1); a2=MFMA(h6,wg2[6],a2); a3=MFMA(h6,wg3[6],a3);
            a0=MFMA(h7,wg0[7],a0); a1=MFMA(h7,wg1[7],a1); a2=MFMA(h7,wg2[7],a2); a3=MFMA(h7,wg3[7],a3);
        }

        // ---- cell update -> scr transpose -> tagged double publish (ASAP) ----
        {
            float gi,gf,gg,go,hv;
            gi=sigf(a0[0]); gf=sigf(a1[0]); gg=tanhf_(a2[0]); go=sigf(a3[0]);
            cs0 = gf*cs0 + gi*gg; hv = go*tanhf_(cs0);
            scr[(mrb+0 + 16*(q>>3))*8 + (q&7)] = f2h(hv);
            gi=sigf(a0[1]); gf=sigf(a1[1]); gg=tanhf_(a2[1]); go=sigf(a3[1]);
            cs1 = gf*cs1 + gi*gg; hv = go*tanhf_(cs1);
            scr[(mrb+1 + 16*(q>>3))*8 + (q&7)] = f2h(hv);
            gi=sigf(a0[2]); gf=sigf(a1[2]); gg=tanhf_(a2[2]); go=sigf(a3[2]);
            cs2 = gf*cs2 + gi*gg; hv = go*tanhf_(cs2);
            scr[(mrb+2 + 16*(q>>3))*8 + (q&7)] = f2h(hv);
            gi=sigf(a0[3]); gf=sigf(a1[3]); gg=tanhf_(a2[3]); go=sigf(a3[3]);
            cs3 = gf*cs3 + gi*gg; hv = go*tanhf_(cs3);
            scr[(mrb+3 + 16*(q>>3))*8 + (q&7)] = f2h(hv);

            u16 w0b=scr[lane*4+0], w1b=scr[lane*4+1], w2b=scr[lane*4+2], w3b=scr[lane*4+3];
            u64 pub = (u64)w0b | ((u64)w1b<<16) | ((u64)w2b<<32) | ((u64)w3b<<48);
            pub = (pub & ~1ull) | (u64)((t>>1)&1);   // generation tag
            const size_t off = (size_t)((t+1)&1)*1024 + kcSelf*128 + gw;
            st_u64_sc0(xpT + off, pub);   // L2 path (same-XCD consumers)
            AGS(xsT + off, pub);          // L3 shadow (universal)
        }

        // ---- off-critical-path: projection of h_{t-1} -> outputs t-1 ----
        if (isP && t > 0) {
            f32x4 pa = {bip,bip,bip,bip};
            pa=MFMA(h0,wp[0],pa); pa=MFMA(h1,wp[1],pa);
            pa=MFMA(h2,wp[2],pa); pa=MFMA(h3,wp[3],pa);
            pa=MFMA(h4,wp[4],pa); pa=MFMA(h5,wp[5],pa);
            pa=MFMA(h6,wp[6],pa); pa=MFMA(h7,wp[7],pa);
            const size_t ob = (size_t)(b0+mrb)*TSTEPS*ODIM + (size_t)(t-1)*ODIM + o_;
            const size_t rs = (size_t)TSTEPS*ODIM;
            outFull[ob+0*rs] = ph0 + pa[0];  outRnn[ob+0*rs] = pa[0];
            outFull[ob+1*rs] = ph1 + pa[1];  outRnn[ob+1*rs] = pa[1];
            outFull[ob+2*rs] = ph2 + pa[2];  outRnn[ob+2*rs] = pa[2];
            outFull[ob+3*rs] = ph3 + pa[3];  outRnn[ob+3*rs] = pa[3];
            const float* pb2 = phys + (size_t)t*BATCH*ODIM + (size_t)(b0+mrb)*ODIM + o_;
            ph0 = pb2[0*ODIM]; ph1 = pb2[1*ODIM]; ph2 = pb2[2*ODIM]; ph3 = pb2[3*ODIM];
        }

        // ---- shift x prefetch (t+2), after poll so it doesn't sit on vmcnt ----
        {
            int tt = (t+2 < TSTEPS) ? (t+2) : (TSTEPS-1);
            const float* p = xbase + (size_t)tt*BATCH*INDIM;
            float4 nn0 = *(const float4*)p;
            float4 nn1 = *(const float4*)(p + 4);
            xc0 = xn0; xc1 = xn1; xn0 = nn0; xn1 = nn1;
        }
    }

    // ---- epilogue (proj waves): poll h_1023 (parity 0, tag 1) -> outputs 1023 ----
    if (isP) {
        const u8*  pb = (const u8*)xpT + lane*16;
        const u64* sb = xsT + lane*2;
        union U { uint4 u; f16x8 h; u64 qq[2]; } A,B,C,D,E,F,G,H;
        int iter = 0;
        for (;;) {
            if (fastm) {
                ld4_sc0(pb,        A.u,B.u,C.u,D.u);
                ld4_sc0(pb + 4096, E.u,F.u,G.u,H.u);
            } else {
                A.qq[0]=AGL(sb+0*128); A.qq[1]=AGL(sb+0*128+1);
                B.qq[0]=AGL(sb+1*128); B.qq[1]=AGL(sb+1*128+1);
                C.qq[0]=AGL(sb+2*128); C.qq[1]=AGL(sb+2*128+1);
                D.qq[0]=AGL(sb+3*128); D.qq[1]=AGL(sb+3*128+1);
                E.qq[0]=AGL(sb+4*128); E.qq[1]=AGL(sb+4*128+1);
                F.qq[0]=AGL(sb+5*128); F.qq[1]=AGL(sb+5*128+1);
                G.qq[0]=AGL(sb+6*128); G.qq[1]=AGL(sb+6*128+1);
                H.qq[0]=AGL(sb+7*128); H.qq[1]=AGL(sb+7*128+1);
            }
            u32 bad = ((A.u.x^1u)|(A.u.z^1u)|(B.u.x^1u)|(B.u.z^1u)
                      |(C.u.x^1u)|(C.u.z^1u)|(D.u.x^1u)|(D.u.z^1u)
                      |(E.u.x^1u)|(E.u.z^1u)|(F.u.x^1u)|(F.u.z^1u)
                      |(G.u.x^1u)|(G.u.z^1u)|(H.u.x^1u)|(H.u.z^1u)) & 1u;
            if (!__any((int)bad)) { h0=A.h;h1=B.h;h2=C.h;h3=D.h;h4=E.h;h5=F.h;h6=G.h;h7=H.h; break; }
            if (fastm && ++iter >= 256) fastm = false;
        }
        f32x4 pa = {bip,bip,bip,bip};
        pa=MFMA(h0,wp[0],pa); pa=MFMA(h1,wp[1],pa);
        pa=MFMA(h2,wp[2],pa); pa=MFMA(h3,wp[3],pa);
        pa=MFMA(h4,wp[4],pa); pa=MFMA(h5,wp[5],pa);
        pa=MFMA(h6,wp[6],pa); pa=MFMA(h7,wp[7],pa);
        const size_t ob = (size_t)(b0+mrb)*TSTEPS*ODIM + (size_t)1023*ODIM + o_;
        const size_t rs = (size_t)TSTEPS*ODIM;
        outFull[ob+0*rs] = ph0 + pa[0];  outRnn[ob+0*rs] = pa[0];
        outFull[ob+1*rs] = ph1 + pa[1];  outRnn[ob+1*rs] = pa[1];
        outFull[ob+2*rs] = ph2 + pa[2];  outRnn[ob+2*rs] = pa[2];
        outFull[ob+3*rs] = ph3 + pa[3];  outRnn[ob+3*rs] = pa[3];
    }
}

extern "C" void kernel_launch(void* const* d_in, const int* in_sizes, int n_in,
                              void* d_out, int out_size, void* d_ws, size_t ws_size,
                              hipStream_t stream) {
    const float* xin   = (const float*)d_in[0];
    const float* phys  = (const float*)d_in[1];
    const float* W_ih  = (const float*)d_in[2];
    const float* W_hh  = (const float*)d_in[3];
    const float* b_ih  = (const float*)d_in[4];
    const float* b_hh  = (const float*)d_in[5];
    const float* W_out = (const float*)d_in[6];
    const float* b_out = (const float*)d_in[7];

    char*  ws = (char*)d_ws;
    u16*   Wb = (u16*)ws;
    float* Bc = (float*)(ws + WS_BC);
    u64*   xp = (u64*)(ws + WS_XP);
    u64*   xs = (u64*)(ws + WS_XS);

    prepack_kernel<<<256, 256, 0, stream>>>(W_ih, W_hh, b_ih, b_hh, W_out, Wb, Bc);
    init_xbuf_kernel<<<256, 256, 0, stream>>>(xp, xs);
    lstm_kernel<<<512, 64, 0, stream>>>(xin, phys, Wb, Bc, b_out, xp, xs, (float*)d_out);
}